// Round 17
// baseline (398.342 us; speedup 1.0000x reference)
//
#include <hip/hip_runtime.h>
#include <hip/hip_bf16.h>
#include <math.h>

#define B_ 64
#define L_ 1024
#define D_ 256
#define C_ 128
#define LPMAX 1536

typedef __bf16 bf16x8 __attribute__((ext_vector_type(8)));
typedef float f32x16 __attribute__((ext_vector_type(16)));

__device__ __forceinline__ unsigned short f2bf(float f) {
    __hip_bfloat16 h = __float2bfloat16(f);
    return __builtin_bit_cast(unsigned short, h);
}

__device__ __forceinline__ float gelu_exact(float f) {
    return 0.5f * f * (1.0f + erff(f * 0.70710678118654752440f));
}

// async global->LDS: global src is per-lane, LDS dest = wave-uniform base + lane*16
__device__ __forceinline__ void gl16(const unsigned short* g, unsigned short* l) {
    __builtin_amdgcn_global_load_lds(
        (const __attribute__((address_space(1))) unsigned int*)g,
        (__attribute__((address_space(3))) unsigned int*)l, 16, 0, 0);
}

// ---- 1. cast x to bf16 + channel-mean series ----
__global__ void prep_kernel(const float* __restrict__ x, unsigned short* __restrict__ xb,
                            float* __restrict__ series) {
    int row = blockIdx.x * 4 + (threadIdx.x >> 6);
    int lane = threadIdx.x & 63;
    size_t base = (size_t)row * D_ + lane * 4;
    float4 v = *reinterpret_cast<const float4*>(x + base);
    ushort4 o;
    o.x = f2bf(v.x); o.y = f2bf(v.y); o.z = f2bf(v.z); o.w = f2bf(v.w);
    *reinterpret_cast<ushort4*>(xb + base) = o;
    float s = v.x + v.y + v.z + v.w;
    #pragma unroll
    for (int d = 32; d; d >>= 1) s += __shfl_xor(s, d);
    if (lane == 0) series[row] = s * (1.0f / D_);
}

// ---- 2. twiddle table (double) ----
__global__ void tw_kernel(double* __restrict__ tw) {
    int j = blockIdx.x * 256 + threadIdx.x;
    if (j < 1024) {
        double a = -2.0 * 3.14159265358979323846 * (double)j / 1024.0;
        tw[2 * j] = cos(a);
        tw[2 * j + 1] = sin(a);
    }
}

// ---- 3. repack weights into per-phase LDS images ----
// W1s: [tap(9)][kk(8)][rb(8)][q(4)][rr(16)][8]  (row=rb*16+rr in 0..127, d=kk*32+q*8+e)
// W2s: [tap(9)][kk(4)][rb(16)][q(4)][rr(16)][8] (row=rb*16+rr in 0..255, c=kk*32+q*8+e)
__global__ void repack_kernel(const float* __restrict__ W1, const float* __restrict__ W2,
                              unsigned short* __restrict__ W1s, unsigned short* __restrict__ W2s) {
    int i = blockIdx.x * 256 + threadIdx.x;
    if (i < 294912) {
        int img = i >> 12;               // tap*8 + kk
        int tap = img >> 3, kk = img & 7;
        int within = i & 4095;
        int rb = within >> 9, q = (within >> 7) & 3, rr = (within >> 3) & 15, e = i & 7;
        int c = rb * 16 + rr, d = kk * 32 + q * 8 + e;
        int dt = tap / 3, dp = tap % 3;
        W1s[i] = f2bf(W1[((c * D_ + d) * 3 + dt) * 3 + dp]);
    } else {
        int i2 = i - 294912;
        if (i2 < 294912) {
            int img = i2 >> 13;          // tap*4 + kk
            int tap = img >> 2, kk = img & 3;
            int within = i2 & 8191;
            int rb = within >> 9, q = (within >> 7) & 3, rr = (within >> 3) & 15, e = i2 & 7;
            int dout = rb * 16 + rr, cin = kk * 32 + q * 8 + e;
            int dt = tap / 3, dp = tap % 3;
            W2s[i2] = f2bf(W2[((dout * C_ + cin) * 3 + dt) * 3 + dp]);
        }
    }
}

// ---- 4. DFT magnitude^2 (double accumulate) ----
__global__ void dft_kernel(const float* __restrict__ series, const double* __restrict__ tw,
                           float* __restrict__ mag2) {
    int bk = blockIdx.x;
    int k = bk % 513, b = bk / 513;
    int lane = threadIdx.x;
    const float* s = series + (size_t)b * L_;
    double re = 0.0, im = 0.0;
    #pragma unroll 4
    for (int i = 0; i < 16; i++) {
        int l = lane + 64 * i;
        int idx = (k * l) & 1023;
        double sv = (double)s[l];
        re += sv * tw[2 * idx];
        im += sv * tw[2 * idx + 1];
    }
    #pragma unroll
    for (int d = 32; d; d >>= 1) { re += __shfl_down(re, d); im += __shfl_down(im, d); }
    if (lane == 0) mag2[bk] = (k == 0) ? 0.0f : (float)(re * re + im * im);
}

// ---- 5. top-3, wave-parallel argmax (tie -> lowest index) ----
__global__ void topk_kernel(const float* __restrict__ mag2, int* __restrict__ periods) {
    int b = blockIdx.x;
    int lane = threadIdx.x;
    const float* m = mag2 + b * 513;
    float v[9]; int kid[9];
    #pragma unroll
    for (int r = 0; r < 9; r++) {
        int k = r * 64 + lane;
        kid[r] = k;
        v[r] = (k < 513) ? m[k] : -1.0f;
    }
    int s0 = -1, s1 = -1;
    for (int j = 0; j < 3; j++) {
        float best = -1.0f; int bi = 0x7fffffff;
        #pragma unroll
        for (int r = 0; r < 9; r++) {
            bool skip = (kid[r] == s0) || (kid[r] == s1) || (kid[r] >= 513);
            if (!skip && (v[r] > best || (v[r] == best && kid[r] < bi))) { best = v[r]; bi = kid[r]; }
        }
        #pragma unroll
        for (int d = 32; d; d >>= 1) {
            float ov = __shfl_xor(best, d);
            int oi = __shfl_xor(bi, d);
            if (ov > best || (ov == best && oi < bi)) { best = ov; bi = oi; }
        }
        if (lane == 0) periods[b * 3 + j] = bi + 1;
        if (j == 0) s0 = bi; else if (j == 1) s1 = bi;
    }
}

// ---- 6. conv1 (256->128) + bias + GELU, output col-major bf16 ----
// 72-sub-phase counted-vmcnt pipeline: sub-phase = (group g=(dt,kk), dp=pos).
// sA = 3-slot ring (slot=dp, 8KB each) refilled 2 sub-phases ahead;
// sB = 2-buffer ring (10 slots + zero) refilled 1 group ahead. 46KB -> 3 blk/CU.
__global__ __launch_bounds__(256, 3)
void conv1_kernel(const unsigned short* __restrict__ xb,
                  const unsigned short* __restrict__ W1s,
                  const float* __restrict__ b1,
                  const int* __restrict__ periods,
                  unsigned short* __restrict__ out1g) {
    __shared__ __align__(16) unsigned short sA[3][4096];   // ring slot = dp
    __shared__ __align__(16) unsigned short sB[2][5632];   // [slot(10)][512]; slot10=zeros

    const int blk = blockIdx.x;
    const int xcd = blk & 7;
    const int li = blk >> 3;            // 0..287
    const int b = xcd * 8 + li / 36;
    const int rem = li % 36;
    const int j = rem / 12, tile = rem % 12;

    const int p = periods[b * 3 + j];
    if (p <= 1) return;
    const int T = (L_ + p - 1) / p;
    const int Lp = T * p;
    const int col0 = tile * 128;
    if (col0 >= Lp) return;

    const int tid = threadIdx.x;
    const int w = tid >> 6, lane = tid & 63;
    const int wm = w >> 1, wn = w & 1;
    const int l15 = lane & 15, l4 = lane >> 4;
    const int l31 = lane & 31, lh = lane >> 5;
    // uniform 3 B-slots per wave (slots 7,8 staged twice with identical data)
    const int s0w = (w == 3) ? 7 : w * 3;

    const unsigned short* xbb = xb + (size_t)b * L_ * D_;

    int cols2[2], ppv2[2], ttv2[2];
    #pragma unroll
    for (int ci = 0; ci < 2; ci++) {
        cols2[ci] = col0 + wn * 64 + ci * 32 + l31;
        ppv2[ci] = cols2[ci] % p;
        ttv2[ci] = cols2[ci] / p;
    }

    int arow32[2];
    #pragma unroll
    for (int ri = 0; ri < 2; ri++)
        arow32[ri] = (wm * 4 + ri * 2 + (l31 >> 4)) * 512 + lh * 128 + (l31 & 15) * 8;
    const int zoff32 = 10 * 512 + lh * 128 + (l31 & 15) * 8;

    f32x16 acc00 = {0.f}, acc01 = {0.f}, acc10 = {0.f}, acc11 = {0.f};

    // zero the redirect slot (slot 10, both buffers)
    {
        int bf = tid >> 7, r = tid & 127;
        ushort4 z = {0, 0, 0, 0};
        *reinterpret_cast<ushort4*>(&sB[bf][10 * 512 + r * 4]) = z;
    }

    int locv[3][2];
    auto setmask = [&](int dt) {
        #pragma unroll
        for (int dp = 0; dp < 3; dp++)
            #pragma unroll
            for (int ci = 0; ci < 2; ci++) {
                int pd = ppv2[ci] + dp, td = ttv2[ci] + dt;
                int t = cols2[ci] + (dt - 1) * p + dp - 1;
                bool ok = (pd >= 1) && (pd <= p) && (td >= 1) && (td <= T) &&
                          (cols2[ci] < Lp) && (t < L_);
                int rc = wn * 64 + ci * 32 + 15 + dp + l31;
                int off = (rc >> 4) * 512 + lh * 128 + (rc & 15) * 8;
                locv[dp][ci] = ok ? off : zoff32;
            }
    };

    const unsigned short* gaB[3];
    auto setaddrB = [&](int dt) {
        const int win1 = col0 + (dt - 1) * p - 16;
        #pragma unroll
        for (int i = 0; i < 3; i++) {
            int c = win1 + (s0w + i) * 16 + l15;
            c = c < 0 ? 0 : (c > L_ - 1 ? L_ - 1 : c);
            gaB[i] = xbb + (size_t)c * D_ + l4 * 8;
        }
    };

    auto stageB = [&](int buf, int kk) {
        unsigned short* lb = sB[buf];
        #pragma unroll
        for (int i = 0; i < 3; i++)
            gl16(gaB[i] + kk * 32, lb + (s0w + i) * 512);
    };

    // stage 8KB image (dt,kk,dp) into ring slot; wave w stages subs 2w, 2w+1
    auto stageA = [&](int slot, int dt, int kk, int dp) {
        const unsigned short* src = W1s + (size_t)((dt * 3 + dp) * 8 + kk) * 4096;
        gl16(src + (w * 2 + 0) * 512 + lane * 8, sA[slot] + (w * 2 + 0) * 512);
        gl16(src + (w * 2 + 1) * 512 + lane * 8, sA[slot] + (w * 2 + 1) * 512);
    };

    // prologue: B(group0), A(u=0 -> slot0), A(u=1 -> slot1)
    setmask(0);
    setaddrB(0);
    stageB(0, 0);
    stageA(0, 0, 0, 0);
    stageA(1, 0, 0, 1);
    asm volatile("s_waitcnt lgkmcnt(0)" ::: "memory");   // zero-slot ds_writes

    int g = 0;
    #pragma unroll 1
    for (int u = 0; u < 72; u++) {
        const int pos = u - g * 3;
        // (a) counted wait BEFORE barrier (cross-wave visibility after barrier)
        if (u == 71) {
            asm volatile("s_waitcnt vmcnt(0)" ::: "memory");
        } else if (u == 70) {
            asm volatile("s_waitcnt vmcnt(2)" ::: "memory");
        } else if (pos == 1) {
            asm volatile("s_waitcnt vmcnt(5)" ::: "memory");
        } else {
            asm volatile("s_waitcnt vmcnt(2)" ::: "memory");
        }
        __builtin_amdgcn_s_barrier();
        __builtin_amdgcn_sched_barrier(0);
        // (c) MFMA: dp = pos, A from ring slot pos, B from sB[g&1]
        __builtin_amdgcn_s_setprio(1);
        {
            const unsigned short* la = sA[pos];
            const unsigned short* lb = sB[g & 1];
            #pragma unroll
            for (int ks = 0; ks < 2; ks++) {
                bf16x8 Af0 = *reinterpret_cast<const bf16x8*>(la + arow32[0] + ks * 256);
                bf16x8 Af1 = *reinterpret_cast<const bf16x8*>(la + arow32[1] + ks * 256);
                bf16x8 Bf0 = *reinterpret_cast<const bf16x8*>(lb + locv[pos][0] + ks * 256);
                bf16x8 Bf1 = *reinterpret_cast<const bf16x8*>(lb + locv[pos][1] + ks * 256);
                acc00 = __builtin_amdgcn_mfma_f32_32x32x16_bf16(Af0, Bf0, acc00, 0, 0, 0);
                acc01 = __builtin_amdgcn_mfma_f32_32x32x16_bf16(Af0, Bf1, acc01, 0, 0, 0);
                acc10 = __builtin_amdgcn_mfma_f32_32x32x16_bf16(Af1, Bf0, acc10, 0, 0, 0);
                acc11 = __builtin_amdgcn_mfma_f32_32x32x16_bf16(Af1, Bf1, acc11, 0, 0, 0);
            }
        }
        __builtin_amdgcn_s_setprio(0);
        __builtin_amdgcn_sched_barrier(0);
        // (d) staging for the future
        if (pos == 0 && g + 1 < 24) {
            const int ng = g + 1, nkk = ng & 7;
            if (nkk == 0) setaddrB(ng >> 3);
            stageB(ng & 1, nkk);
        }
        if (u + 2 < 72) {
            const int u2 = u + 2, g2 = u2 / 3, p2 = u2 - g2 * 3;
            stageA(p2, g2 >> 3, g2 & 7, p2);
        }
        if (pos == 2) {
            if (((g + 1) & 7) == 0 && g + 1 < 24) setmask((g + 1) >> 3);
            g++;
        }
    }

    const size_t ob = (size_t)(b * 3 + j) * LPMAX * C_;
    const f32x16* accs[4] = { &acc00, &acc01, &acc10, &acc11 };
    #pragma unroll
    for (int ri = 0; ri < 2; ri++) {
        #pragma unroll
        for (int ci = 0; ci < 2; ci++) {
            const f32x16& a = *accs[ri * 2 + ci];
            const int c = cols2[ci];
            if (c < Lp) {
                #pragma unroll
                for (int t = 0; t < 4; t++) {
                    const int ch = wm * 64 + ri * 32 + t * 8 + 4 * lh;
                    const float4 bias = *reinterpret_cast<const float4*>(b1 + ch);
                    ushort4 o;
                    o.x = f2bf(gelu_exact(a[t * 4 + 0] + bias.x));
                    o.y = f2bf(gelu_exact(a[t * 4 + 1] + bias.y));
                    o.z = f2bf(gelu_exact(a[t * 4 + 2] + bias.z));
                    o.w = f2bf(gelu_exact(a[t * 4 + 3] + bias.w));
                    *reinterpret_cast<ushort4*>(out1g + ob + (size_t)c * C_ + ch) = o;
                }
            }
        }
    }
}

// ---- 7. conv2 (128->256) + residual + FUSED LayerNorm; writes final out ----
__global__ __launch_bounds__(256, 2)
void conv2_kernel(const unsigned short* __restrict__ out1g,
                  const unsigned short* __restrict__ W2s,
                  const float* __restrict__ b2,
                  const int* __restrict__ periods,
                  const float* __restrict__ x,
                  const float* __restrict__ gamma,
                  const float* __restrict__ beta,
                  float* __restrict__ yout) {
    __shared__ __align__(16) unsigned short sA[24576];     // [dp(3)][rb(16)][512]
    __shared__ __align__(16) unsigned short sB[2][5632];   // [slot(10)+zero][512]

    const int blk = blockIdx.x;
    const int xcd = blk & 7;
    const int li = blk >> 3;            // 0..63
    const int b = xcd * 8 + (li >> 3);
    const int tile = li & 7;
    const int col0 = tile * 128;

    const int tid = threadIdx.x;
    const int w = tid >> 6, lane = tid & 63;
    const int wm = w >> 1, wn = w & 1;
    const int l15 = lane & 15, l4 = lane >> 4;
    const int l31 = lane & 31, lh = lane >> 5;
    const int s0w = (w < 2) ? w * 3 : 6 + (w - 2) * 2;
    const int nsw = (w < 2) ? 3 : 2;
    const int wcol = wn * 64;

    int p_all[3];
    #pragma unroll
    for (int jj = 0; jj < 3; jj++) p_all[jj] = periods[b * 3 + jj];
    const int nv = (p_all[0] > 1) + (p_all[1] > 1) + (p_all[2] > 1);

    int cols2[2];
    #pragma unroll
    for (int ci = 0; ci < 2; ci++) cols2[ci] = col0 + wcol + ci * 32 + l31;

    int arow32[4];
    #pragma unroll
    for (int ri = 0; ri < 4; ri++)
        arow32[ri] = (wm * 8 + ri * 2 + (l31 >> 4)) * 512 + lh * 128 + (l31 & 15) * 8;
    const int zoff32 = 10 * 512 + lh * 128 + (l31 & 15) * 8;

    f32x16 acc[4][2];
    #pragma unroll
    for (int ri = 0; ri < 4; ri++)
        #pragma unroll
        for (int ci = 0; ci < 2; ci++)
            acc[ri][ci] = f32x16{0.f};

    {
        int bf = tid >> 7, r = tid & 127;
        ushort4 z = {0, 0, 0, 0};
        *reinterpret_cast<ushort4*>(&sB[bf][10 * 512 + r * 4]) = z;
    }

    int locv[3][2];
    auto setmask = [&](int jn, int dt) {
        const int pj = p_all[jn];
        const int Tj = (L_ + pj - 1) / pj;
        const bool okj = pj > 1;
        #pragma unroll
        for (int dp = 0; dp < 3; dp++)
            #pragma unroll
            for (int ci = 0; ci < 2; ci++) {
                int pv = cols2[ci] % pj, tv = cols2[ci] / pj;
                int pd = pv + dp, td = tv + dt;
                bool ok = okj && (pd >= 1) && (pd <= pj) && (td >= 1) && (td <= Tj);
                int rc = wcol + ci * 32 + 15 + dp + l31;
                int off = (rc >> 4) * 512 + lh * 128 + (rc & 15) * 8;
                locv[dp][ci] = ok ? off : zoff32;
            }
    };

    const unsigned short* gaB[3];
    auto setaddrB = [&](int jn, int dt) {
        const int pj = p_all[jn];
        const unsigned short* bbj = out1g + (size_t)(b * 3 + jn) * LPMAX * C_;
        const int win1 = col0 + (dt - 1) * pj - 16;
        #pragma unroll
        for (int i = 0; i < 3; i++) {
            int c = win1 + (s0w + i) * 16 + l15;
            c = c < 0 ? 0 : (c > LPMAX - 1 ? LPMAX - 1 : c);
            gaB[i] = bbj + (size_t)c * C_ + l4 * 8;
        }
    };

    auto stageB = [&](int buf, int kk) {
        unsigned short* lb = sB[buf];
        #pragma unroll
        for (int i = 0; i < 3; i++)
            if (i < nsw) gl16(gaB[i] + kk * 32, lb + (s0w + i) * 512);
    };

    auto stageA = [&](int dt, int kk) {
        #pragma unroll
        for (int s12 = 0; s12 < 12; s12++) {
            int pi = w * 12 + s12;
            int dp = pi >> 4, sub = pi & 15;
            gl16(W2s + (size_t)((dt * 3 + dp) * 4 + kk) * 8192 + sub * 512 + lane * 8,
                 sA + pi * 512);
        }
    };

    setmask(0, 0);
    setaddrB(0, 0);
    stageB(0, 0);
    stageA(0, 0);

    for (int ph = 0; ph < 36; ph++) {
        const int cur = ph & 1;
        const int pn = ph + 1;
        asm volatile("s_waitcnt vmcnt(0)" ::: "memory");
        __builtin_amdgcn_s_barrier();
        __builtin_amdgcn_sched_barrier(0);
        if (pn < 36) {
            if ((pn & 3) == 0) setaddrB(pn / 12, (pn / 4) % 3);
            stageB(cur ^ 1, pn & 3);
        }
        __builtin_amdgcn_sched_barrier(0);
        __builtin_amdgcn_s_setprio(1);
        {
            const unsigned short* lb = sB[cur];
            #pragma unroll
            for (int dp = 0; dp < 3; dp++) {
                #pragma unroll
                for (int ks = 0; ks < 2; ks++) {
                    bf16x8 Bf0 = *reinterpret_cast<const bf16x8*>(lb + locv[dp][0] + ks * 256);
                    bf16x8 Bf1 = *reinterpret_cast<const bf16x8*>(lb + locv[dp][1] + ks * 256);
                    #pragma unroll
                    for (int ri = 0; ri < 4; ri++) {
                        bf16x8 Af = *reinterpret_cast<const bf16x8*>(sA + dp * 8192 + arow32[ri] + ks * 256);
                        acc[ri][0] = __builtin_amdgcn_mfma_f32_32x32x16_bf16(Af, Bf0, acc[ri][0], 0, 0, 0);
                        acc[ri][1] = __builtin_amdgcn_mfma_f32_32x32x16_bf16(Af, Bf1, acc[ri][1], 0, 0, 0);
                    }
                }
            }
        }
        __builtin_amdgcn_s_setprio(0);
        asm volatile("s_waitcnt lgkmcnt(0)" ::: "memory");
        __builtin_amdgcn_sched_barrier(0);
        __builtin_amdgcn_s_barrier();
        if (pn < 36) {
            stageA((pn / 4) % 3, pn & 3);
            if ((pn & 3) == 0) setmask(pn / 12, (pn / 4) % 3);
        }
    }

    // ---- epilogue: y = x + (acc + nv*b2)/3, then fused LayerNorm over D ----
    const float inv3 = 1.0f / 3.0f;
    const float fnv = (float)nv;
    float sum2[2] = {0.f, 0.f}, ssq2[2] = {0.f, 0.f};
    #pragma unroll
    for (int ri = 0; ri < 4; ri++) {
        #pragma unroll
        for (int ci = 0; ci < 2; ci++) {
            const int c = cols2[ci];
            #pragma unroll
            for (int t = 0; t < 4; t++) {
                const int dout = wm * 128 + ri * 32 + t * 8 + 4 * lh;
                const float4 bb = *reinterpret_cast<const float4*>(b2 + dout);
                const size_t xoff = ((size_t)b * L_ + c) * D_ + dout;
                const float4 xr = *reinterpret_cast<const float4*>(x + xoff);
                float y0 = xr.x + (acc[ri][ci][t * 4 + 0] + fnv * bb.x) * inv3;
                float y1 = xr.y + (acc[ri][ci][t * 4 + 1] + fnv * bb.y) * inv3;
                float y2 = xr.z + (acc[ri][ci][t * 4 + 2] + fnv * bb.z) * inv3;
                float y3 = xr.w + (acc[ri][ci][t * 4 + 3] + fnv * bb.w) * inv3;
                acc[ri][ci][t * 4 + 0] = y0;
                acc[ri][ci][t * 4 + 1] = y1;
                acc[ri][ci][t * 4 + 2] = y2;
                acc[ri][ci][t * 4 + 3] = y3;
                sum2[ci] += y0 + y1 + y2 + y3;
                ssq2[ci] += y0 * y0 + y1 * y1 + y2 * y2 + y3 * y3;
            }
        }
    }
    #pragma unroll
    for (int ci = 0; ci < 2; ci++) {
        sum2[ci] += __shfl_xor(sum2[ci], 32);
        ssq2[ci] += __shfl_xor(ssq2[ci], 32);
    }
    float* red = (float*)&sB[0][0];
    if (lh == 0) {
        #pragma unroll
        for (int ci = 0; ci < 2; ci++) {
            red[((w * 2 + ci) * 32 + l31) * 2 + 0] = sum2[ci];
            red[((w * 2 + ci) * 32 + l31) * 2 + 1] = ssq2[ci];
        }
    }
    __syncthreads();
    float muv[2], invv[2];
    #pragma unroll
    for (int ci = 0; ci < 2; ci++) {
        float ts = red[((wn * 2 + ci) * 32 + l31) * 2 + 0] +
                   red[(((2 + wn) * 2 + ci) * 32 + l31) * 2 + 0];
        float tq = red[((wn * 2 + ci) * 32 + l31) * 2 + 1] +
                   red[(((2 + wn) * 2 + ci) * 32 + l31) * 2 + 1];
        float mu = ts * (1.0f / 256.0f);
        float var = tq * (1.0f / 256.0f) - mu * mu;
        muv[ci] = mu;
        invv[ci] = 1.0f / sqrtf(var + 1e-5f);
    }
    #pragma unroll
    for (int ri = 0; ri < 4; ri++) {
        #pragma unroll
        for (int ci = 0; ci < 2; ci++) {
            const int c = cols2[ci];
            const float mu = muv[ci], inv = invv[ci];
            #pragma unroll
            for (int t = 0; t < 4; t++) {
                const int dout = wm * 128 + ri * 32 + t * 8 + 4 * lh;
                const float4 g4 = *reinterpret_cast<const float4*>(gamma + dout);
                const float4 be4 = *reinterpret_cast<const float4*>(beta + dout);
                const size_t xoff = ((size_t)b * L_ + c) * D_ + dout;
                float4 o;
                o.x = (acc[ri][ci][t * 4 + 0] - mu) * inv * g4.x + be4.x;
                o.y = (acc[ri][ci][t * 4 + 1] - mu) * inv * g4.y + be4.y;
                o.z = (acc[ri][ci][t * 4 + 2] - mu) * inv * g4.z + be4.z;
                o.w = (acc[ri][ci][t * 4 + 3] - mu) * inv * g4.w + be4.w;
                *reinterpret_cast<float4*>(yout + xoff) = o;
            }
        }
    }
}

extern "C" void kernel_launch(void* const* d_in, const int* in_sizes, int n_in,
                              void* d_out, int out_size, void* d_ws, size_t ws_size,
                              hipStream_t stream) {
    const float* x     = (const float*)d_in[0];
    const float* W1    = (const float*)d_in[1];
    const float* b1    = (const float*)d_in[2];
    const float* W2    = (const float*)d_in[3];
    const float* b2    = (const float*)d_in[4];
    const float* gamma = (const float*)d_in[5];
    const float* beta  = (const float*)d_in[6];
    float* out = (float*)d_out;

    char* ws = (char*)d_ws;
    size_t off = 0;
    auto walloc = [&](size_t bytes) -> void* {
        void* pp = ws + off;
        off += (bytes + 255) & ~(size_t)255;
        return pp;
    };
    unsigned short* xb    = (unsigned short*)walloc((size_t)B_ * L_ * D_ * 2);
    unsigned short* out1g = (unsigned short*)walloc((size_t)B_ * 3 * LPMAX * C_ * 2);
    float* series         = (float*)walloc((size_t)B_ * L_ * 4);
    float* mag2           = (float*)walloc((size_t)B_ * 513 * 4);
    int* periods          = (int*)walloc((size_t)B_ * 3 * 4);
    double* tw            = (double*)walloc(1024 * 16);
    unsigned short* W1s   = (unsigned short*)walloc((size_t)294912 * 2);
    unsigned short* W2s   = (unsigned short*)walloc((size_t)294912 * 2);

    prep_kernel<<<B_ * L_ / 4, 256, 0, stream>>>(x, xb, series);
    tw_kernel<<<4, 256, 0, stream>>>(tw);
    repack_kernel<<<2304, 256, 0, stream>>>(W1, W2, W1s, W2s);
    dft_kernel<<<B_ * 513, 64, 0, stream>>>(series, tw, mag2);
    topk_kernel<<<B_, 64, 0, stream>>>(mag2, periods);
    conv1_kernel<<<B_ * 3 * 12, 256, 0, stream>>>(xb, W1s, b1, periods, out1g);
    conv2_kernel<<<B_ * 8, 256, 0, stream>>>(out1g, W2s, b2, periods, x, gamma, beta, out);
}

// Round 18
// 361.844 us; speedup vs baseline: 1.1009x; 1.1009x over previous
//
#include <hip/hip_runtime.h>
#include <hip/hip_bf16.h>
#include <math.h>

#define B_ 64
#define L_ 1024
#define D_ 256
#define C_ 128
#define LPMAX 1536

typedef __bf16 bf16x8 __attribute__((ext_vector_type(8)));
typedef float f32x16 __attribute__((ext_vector_type(16)));

__device__ __forceinline__ unsigned short f2bf(float f) {
    __hip_bfloat16 h = __float2bfloat16(f);
    return __builtin_bit_cast(unsigned short, h);
}

__device__ __forceinline__ float gelu_exact(float f) {
    return 0.5f * f * (1.0f + erff(f * 0.70710678118654752440f));
}

// async global->LDS: global src is per-lane, LDS dest = wave-uniform base + lane*16
__device__ __forceinline__ void gl16(const unsigned short* g, unsigned short* l) {
    __builtin_amdgcn_global_load_lds(
        (const __attribute__((address_space(1))) unsigned int*)g,
        (__attribute__((address_space(3))) unsigned int*)l, 16, 0, 0);
}

// ---- 1. cast x to bf16 + channel-mean series ----
__global__ void prep_kernel(const float* __restrict__ x, unsigned short* __restrict__ xb,
                            float* __restrict__ series) {
    int row = blockIdx.x * 4 + (threadIdx.x >> 6);
    int lane = threadIdx.x & 63;
    size_t base = (size_t)row * D_ + lane * 4;
    float4 v = *reinterpret_cast<const float4*>(x + base);
    ushort4 o;
    o.x = f2bf(v.x); o.y = f2bf(v.y); o.z = f2bf(v.z); o.w = f2bf(v.w);
    *reinterpret_cast<ushort4*>(xb + base) = o;
    float s = v.x + v.y + v.z + v.w;
    #pragma unroll
    for (int d = 32; d; d >>= 1) s += __shfl_xor(s, d);
    if (lane == 0) series[row] = s * (1.0f / D_);
}

// ---- 2. twiddle table (double) ----
__global__ void tw_kernel(double* __restrict__ tw) {
    int j = blockIdx.x * 256 + threadIdx.x;
    if (j < 1024) {
        double a = -2.0 * 3.14159265358979323846 * (double)j / 1024.0;
        tw[2 * j] = cos(a);
        tw[2 * j + 1] = sin(a);
    }
}

// ---- 3. repack weights into per-phase LDS images ----
// W1s: [tap(9)][kk(8)][rb(8)][q(4)][rr(16)][8]  (row=rb*16+rr in 0..127, d=kk*32+q*8+e)
// W2s: [tap(9)][kk(4)][rb(16)][q(4)][rr(16)][8] (row=rb*16+rr in 0..255, c=kk*32+q*8+e)
__global__ void repack_kernel(const float* __restrict__ W1, const float* __restrict__ W2,
                              unsigned short* __restrict__ W1s, unsigned short* __restrict__ W2s) {
    int i = blockIdx.x * 256 + threadIdx.x;
    if (i < 294912) {
        int img = i >> 12;               // tap*8 + kk
        int tap = img >> 3, kk = img & 7;
        int within = i & 4095;
        int rb = within >> 9, q = (within >> 7) & 3, rr = (within >> 3) & 15, e = i & 7;
        int c = rb * 16 + rr, d = kk * 32 + q * 8 + e;
        int dt = tap / 3, dp = tap % 3;
        W1s[i] = f2bf(W1[((c * D_ + d) * 3 + dt) * 3 + dp]);
    } else {
        int i2 = i - 294912;
        if (i2 < 294912) {
            int img = i2 >> 13;          // tap*4 + kk
            int tap = img >> 2, kk = img & 3;
            int within = i2 & 8191;
            int rb = within >> 9, q = (within >> 7) & 3, rr = (within >> 3) & 15, e = i2 & 7;
            int dout = rb * 16 + rr, cin = kk * 32 + q * 8 + e;
            int dt = tap / 3, dp = tap % 3;
            W2s[i2] = f2bf(W2[((dout * C_ + cin) * 3 + dt) * 3 + dp]);
        }
    }
}

// ---- 4. DFT magnitude^2 (double accumulate); 4 (b,k) pairs per 256-thr block ----
__global__ void dft_kernel(const float* __restrict__ series, const double* __restrict__ tw,
                           float* __restrict__ mag2) {
    int idx = blockIdx.x * 4 + (threadIdx.x >> 6);
    if (idx >= B_ * 513) return;
    int k = idx % 513, b = idx / 513;
    int lane = threadIdx.x & 63;
    const float* s = series + (size_t)b * L_;
    double re = 0.0, im = 0.0;
    #pragma unroll 4
    for (int i = 0; i < 16; i++) {
        int l = lane + 64 * i;
        int ti = (k * l) & 1023;
        double sv = (double)s[l];
        re += sv * tw[2 * ti];
        im += sv * tw[2 * ti + 1];
    }
    #pragma unroll
    for (int d = 32; d; d >>= 1) { re += __shfl_down(re, d); im += __shfl_down(im, d); }
    if (lane == 0) mag2[idx] = (k == 0) ? 0.0f : (float)(re * re + im * im);
}

// ---- 5. top-3, wave-parallel argmax (tie -> lowest index) ----
__global__ void topk_kernel(const float* __restrict__ mag2, int* __restrict__ periods) {
    int b = blockIdx.x;
    int lane = threadIdx.x;
    const float* m = mag2 + b * 513;
    float v[9]; int kid[9];
    #pragma unroll
    for (int r = 0; r < 9; r++) {
        int k = r * 64 + lane;
        kid[r] = k;
        v[r] = (k < 513) ? m[k] : -1.0f;
    }
    int s0 = -1, s1 = -1;
    for (int j = 0; j < 3; j++) {
        float best = -1.0f; int bi = 0x7fffffff;
        #pragma unroll
        for (int r = 0; r < 9; r++) {
            bool skip = (kid[r] == s0) || (kid[r] == s1) || (kid[r] >= 513);
            if (!skip && (v[r] > best || (v[r] == best && kid[r] < bi))) { best = v[r]; bi = kid[r]; }
        }
        #pragma unroll
        for (int d = 32; d; d >>= 1) {
            float ov = __shfl_xor(best, d);
            int oi = __shfl_xor(bi, d);
            if (ov > best || (ov == best && oi < bi)) { best = ov; bi = oi; }
        }
        if (lane == 0) periods[b * 3 + j] = bi + 1;
        if (j == 0) s0 = bi; else if (j == 1) s1 = bi;
    }
}

// ---- 6. conv1 (256->128) + bias + GELU, output col-major bf16 ----
// r16 optimum: 128x128 tile, 32x32 MFMA, A single-buf gl16, B 10-slot dbuf,
// 46KB LDS -> 3 blk/CU, 24 phases x 24 MFMA.
__global__ __launch_bounds__(256, 3)
void conv1_kernel(const unsigned short* __restrict__ xb,
                  const unsigned short* __restrict__ W1s,
                  const float* __restrict__ b1,
                  const int* __restrict__ periods,
                  unsigned short* __restrict__ out1g) {
    __shared__ __align__(16) unsigned short sA[12288];     // [dp(3)][sub(8)][512] single buffer
    __shared__ __align__(16) unsigned short sB[2][5632];   // [slot(10)][512]; slot10=zeros

    const int blk = blockIdx.x;
    const int xcd = blk & 7;
    const int li = blk >> 3;            // 0..287
    const int b = xcd * 8 + li / 36;
    const int rem = li % 36;
    const int j = rem / 12, tile = rem % 12;

    const int p = periods[b * 3 + j];
    if (p <= 1) return;
    const int T = (L_ + p - 1) / p;
    const int Lp = T * p;
    const int col0 = tile * 128;
    if (col0 >= Lp) return;

    const int tid = threadIdx.x;
    const int w = tid >> 6, lane = tid & 63;
    const int wm = w >> 1, wn = w & 1;
    const int l15 = lane & 15, l4 = lane >> 4;
    const int l31 = lane & 31, lh = lane >> 5;
    const int s0w = (w < 2) ? w * 3 : 6 + (w - 2) * 2;   // B slot base per wave
    const int nsw = (w < 2) ? 3 : 2;                     // B slots per wave

    const unsigned short* xbb = xb + (size_t)b * L_ * D_;

    int cols2[2], ppv2[2], ttv2[2];
    #pragma unroll
    for (int ci = 0; ci < 2; ci++) {
        cols2[ci] = col0 + wn * 64 + ci * 32 + l31;
        ppv2[ci] = cols2[ci] % p;
        ttv2[ci] = cols2[ci] / p;
    }

    int arow32[2];
    #pragma unroll
    for (int ri = 0; ri < 2; ri++)
        arow32[ri] = (wm * 4 + ri * 2 + (l31 >> 4)) * 512 + lh * 128 + (l31 & 15) * 8;
    const int zoff32 = 10 * 512 + lh * 128 + (l31 & 15) * 8;

    f32x16 acc00 = {0.f}, acc01 = {0.f}, acc10 = {0.f}, acc11 = {0.f};

    // zero the redirect slot (slot 10, both buffers)
    {
        int bf = tid >> 7, r = tid & 127;
        ushort4 z = {0, 0, 0, 0};
        *reinterpret_cast<ushort4*>(&sB[bf][10 * 512 + r * 4]) = z;
    }

    int locv[3][2];
    auto setmask = [&](int dt) {
        #pragma unroll
        for (int dp = 0; dp < 3; dp++)
            #pragma unroll
            for (int ci = 0; ci < 2; ci++) {
                int pd = ppv2[ci] + dp, td = ttv2[ci] + dt;
                int t = cols2[ci] + (dt - 1) * p + dp - 1;
                bool ok = (pd >= 1) && (pd <= p) && (td >= 1) && (td <= T) &&
                          (cols2[ci] < Lp) && (t < L_);
                int rc = wn * 64 + ci * 32 + 15 + dp + l31;
                int off = (rc >> 4) * 512 + lh * 128 + (rc & 15) * 8;
                locv[dp][ci] = ok ? off : zoff32;
            }
    };

    const unsigned short* gaB[3];
    auto setaddrB = [&](int dt) {
        const int win1 = col0 + (dt - 1) * p - 16;
        #pragma unroll
        for (int i = 0; i < 3; i++) {
            int c = win1 + (s0w + i) * 16 + l15;
            c = c < 0 ? 0 : (c > L_ - 1 ? L_ - 1 : c);
            gaB[i] = xbb + (size_t)c * D_ + l4 * 8;
        }
    };

    auto stageB = [&](int buf, int kk) {
        unsigned short* lb = sB[buf];
        #pragma unroll
        for (int i = 0; i < 3; i++)
            if (i < nsw) gl16(gaB[i] + kk * 32, lb + (s0w + i) * 512);
    };

    auto stageA = [&](int dt, int kk) {
        #pragma unroll
        for (int s6 = 0; s6 < 6; s6++) {
            int pi = w * 6 + s6;
            int dp = pi >> 3, sub = pi & 7;
            gl16(W1s + (size_t)((dt * 3 + dp) * 8 + kk) * 4096 + sub * 512 + lane * 8,
                 sA + pi * 512);
        }
    };

    setmask(0);
    setaddrB(0);
    stageB(0, 0);
    stageA(0, 0);
    asm volatile("s_waitcnt lgkmcnt(0)" ::: "memory");

    for (int ph = 0; ph < 24; ph++) {
        const int cur = ph & 1;
        const int pn = ph + 1;
        asm volatile("s_waitcnt vmcnt(0)" ::: "memory");
        __builtin_amdgcn_s_barrier();
        __builtin_amdgcn_sched_barrier(0);
        if (pn < 24) {                       // B for next phase: ages under this MFMA phase
            if ((pn & 7) == 0) setaddrB(pn >> 3);
            stageB(cur ^ 1, pn & 7);
        }
        __builtin_amdgcn_sched_barrier(0);
        __builtin_amdgcn_s_setprio(1);
        {
            const unsigned short* lb = sB[cur];
            #pragma unroll
            for (int dp = 0; dp < 3; dp++) {
                #pragma unroll
                for (int ks = 0; ks < 2; ks++) {
                    bf16x8 Af0 = *reinterpret_cast<const bf16x8*>(sA + dp * 4096 + arow32[0] + ks * 256);
                    bf16x8 Af1 = *reinterpret_cast<const bf16x8*>(sA + dp * 4096 + arow32[1] + ks * 256);
                    bf16x8 Bf0 = *reinterpret_cast<const bf16x8*>(lb + locv[dp][0] + ks * 256);
                    bf16x8 Bf1 = *reinterpret_cast<const bf16x8*>(lb + locv[dp][1] + ks * 256);
                    acc00 = __builtin_amdgcn_mfma_f32_32x32x16_bf16(Af0, Bf0, acc00, 0, 0, 0);
                    acc01 = __builtin_amdgcn_mfma_f32_32x32x16_bf16(Af0, Bf1, acc01, 0, 0, 0);
                    acc10 = __builtin_amdgcn_mfma_f32_32x32x16_bf16(Af1, Bf0, acc10, 0, 0, 0);
                    acc11 = __builtin_amdgcn_mfma_f32_32x32x16_bf16(Af1, Bf1, acc11, 0, 0, 0);
                }
            }
        }
        __builtin_amdgcn_s_setprio(0);
        asm volatile("s_waitcnt lgkmcnt(0)" ::: "memory");   // my sA ds_reads retired
        __builtin_amdgcn_sched_barrier(0);
        __builtin_amdgcn_s_barrier();                        // all waves done reading sA
        if (pn < 24) {
            stageA(pn >> 3, pn & 7);
            if ((pn & 7) == 0) setmask(pn >> 3);
        }
    }

    const size_t ob = (size_t)(b * 3 + j) * LPMAX * C_;
    const f32x16* accs[4] = { &acc00, &acc01, &acc10, &acc11 };
    #pragma unroll
    for (int ri = 0; ri < 2; ri++) {
        #pragma unroll
        for (int ci = 0; ci < 2; ci++) {
            const f32x16& a = *accs[ri * 2 + ci];
            const int c = cols2[ci];
            if (c < Lp) {
                #pragma unroll
                for (int t = 0; t < 4; t++) {
                    const int ch = wm * 64 + ri * 32 + t * 8 + 4 * lh;
                    const float4 bias = *reinterpret_cast<const float4*>(b1 + ch);
                    ushort4 o;
                    o.x = f2bf(gelu_exact(a[t * 4 + 0] + bias.x));
                    o.y = f2bf(gelu_exact(a[t * 4 + 1] + bias.y));
                    o.z = f2bf(gelu_exact(a[t * 4 + 2] + bias.z));
                    o.w = f2bf(gelu_exact(a[t * 4 + 3] + bias.w));
                    *reinterpret_cast<ushort4*>(out1g + ob + (size_t)c * C_ + ch) = o;
                }
            }
        }
    }
}

// ---- 7. conv2 (128->256) + residual + FUSED LayerNorm; writes final out ----
__global__ __launch_bounds__(256, 2)
void conv2_kernel(const unsigned short* __restrict__ out1g,
                  const unsigned short* __restrict__ W2s,
                  const float* __restrict__ b2,
                  const int* __restrict__ periods,
                  const float* __restrict__ x,
                  const float* __restrict__ gamma,
                  const float* __restrict__ beta,
                  float* __restrict__ yout) {
    __shared__ __align__(16) unsigned short sA[24576];     // [dp(3)][rb(16)][512]
    __shared__ __align__(16) unsigned short sB[2][5632];   // [slot(10)+zero][512]

    const int blk = blockIdx.x;
    const int xcd = blk & 7;
    const int li = blk >> 3;            // 0..63
    const int b = xcd * 8 + (li >> 3);
    const int tile = li & 7;
    const int col0 = tile * 128;

    const int tid = threadIdx.x;
    const int w = tid >> 6, lane = tid & 63;
    const int wm = w >> 1, wn = w & 1;
    const int l15 = lane & 15, l4 = lane >> 4;
    const int l31 = lane & 31, lh = lane >> 5;
    const int s0w = (w < 2) ? w * 3 : 6 + (w - 2) * 2;
    const int nsw = (w < 2) ? 3 : 2;
    const int wcol = wn * 64;

    int p_all[3];
    #pragma unroll
    for (int jj = 0; jj < 3; jj++) p_all[jj] = periods[b * 3 + jj];
    const int nv = (p_all[0] > 1) + (p_all[1] > 1) + (p_all[2] > 1);

    int cols2[2];
    #pragma unroll
    for (int ci = 0; ci < 2; ci++) cols2[ci] = col0 + wcol + ci * 32 + l31;

    int arow32[4];
    #pragma unroll
    for (int ri = 0; ri < 4; ri++)
        arow32[ri] = (wm * 8 + ri * 2 + (l31 >> 4)) * 512 + lh * 128 + (l31 & 15) * 8;
    const int zoff32 = 10 * 512 + lh * 128 + (l31 & 15) * 8;

    f32x16 acc[4][2];
    #pragma unroll
    for (int ri = 0; ri < 4; ri++)
        #pragma unroll
        for (int ci = 0; ci < 2; ci++)
            acc[ri][ci] = f32x16{0.f};

    {
        int bf = tid >> 7, r = tid & 127;
        ushort4 z = {0, 0, 0, 0};
        *reinterpret_cast<ushort4*>(&sB[bf][10 * 512 + r * 4]) = z;
    }

    int locv[3][2];
    auto setmask = [&](int jn, int dt) {
        const int pj = p_all[jn];
        const int Tj = (L_ + pj - 1) / pj;
        const bool okj = pj > 1;
        #pragma unroll
        for (int dp = 0; dp < 3; dp++)
            #pragma unroll
            for (int ci = 0; ci < 2; ci++) {
                int pv = cols2[ci] % pj, tv = cols2[ci] / pj;
                int pd = pv + dp, td = tv + dt;
                bool ok = okj && (pd >= 1) && (pd <= pj) && (td >= 1) && (td <= Tj);
                int rc = wcol + ci * 32 + 15 + dp + l31;
                int off = (rc >> 4) * 512 + lh * 128 + (rc & 15) * 8;
                locv[dp][ci] = ok ? off : zoff32;
            }
    };

    const unsigned short* gaB[3];
    auto setaddrB = [&](int jn, int dt) {
        const int pj = p_all[jn];
        const unsigned short* bbj = out1g + (size_t)(b * 3 + jn) * LPMAX * C_;
        const int win1 = col0 + (dt - 1) * pj - 16;
        #pragma unroll
        for (int i = 0; i < 3; i++) {
            int c = win1 + (s0w + i) * 16 + l15;
            c = c < 0 ? 0 : (c > LPMAX - 1 ? LPMAX - 1 : c);
            gaB[i] = bbj + (size_t)c * C_ + l4 * 8;
        }
    };

    auto stageB = [&](int buf, int kk) {
        unsigned short* lb = sB[buf];
        #pragma unroll
        for (int i = 0; i < 3; i++)
            if (i < nsw) gl16(gaB[i] + kk * 32, lb + (s0w + i) * 512);
    };

    auto stageA = [&](int dt, int kk) {
        #pragma unroll
        for (int s12 = 0; s12 < 12; s12++) {
            int pi = w * 12 + s12;
            int dp = pi >> 4, sub = pi & 15;
            gl16(W2s + (size_t)((dt * 3 + dp) * 4 + kk) * 8192 + sub * 512 + lane * 8,
                 sA + pi * 512);
        }
    };

    setmask(0, 0);
    setaddrB(0, 0);
    stageB(0, 0);
    stageA(0, 0);

    for (int ph = 0; ph < 36; ph++) {
        const int cur = ph & 1;
        const int pn = ph + 1;
        asm volatile("s_waitcnt vmcnt(0)" ::: "memory");
        __builtin_amdgcn_s_barrier();
        __builtin_amdgcn_sched_barrier(0);
        if (pn < 36) {
            if ((pn & 3) == 0) setaddrB(pn / 12, (pn / 4) % 3);
            stageB(cur ^ 1, pn & 3);
        }
        __builtin_amdgcn_sched_barrier(0);
        __builtin_amdgcn_s_setprio(1);
        {
            const unsigned short* lb = sB[cur];
            #pragma unroll
            for (int dp = 0; dp < 3; dp++) {
                #pragma unroll
                for (int ks = 0; ks < 2; ks++) {
                    bf16x8 Bf0 = *reinterpret_cast<const bf16x8*>(lb + locv[dp][0] + ks * 256);
                    bf16x8 Bf1 = *reinterpret_cast<const bf16x8*>(lb + locv[dp][1] + ks * 256);
                    #pragma unroll
                    for (int ri = 0; ri < 4; ri++) {
                        bf16x8 Af = *reinterpret_cast<const bf16x8*>(sA + dp * 8192 + arow32[ri] + ks * 256);
                        acc[ri][0] = __builtin_amdgcn_mfma_f32_32x32x16_bf16(Af, Bf0, acc[ri][0], 0, 0, 0);
                        acc[ri][1] = __builtin_amdgcn_mfma_f32_32x32x16_bf16(Af, Bf1, acc[ri][1], 0, 0, 0);
                    }
                }
            }
        }
        __builtin_amdgcn_s_setprio(0);
        asm volatile("s_waitcnt lgkmcnt(0)" ::: "memory");
        __builtin_amdgcn_sched_barrier(0);
        __builtin_amdgcn_s_barrier();
        if (pn < 36) {
            stageA((pn / 4) % 3, pn & 3);
            if ((pn & 3) == 0) setmask(pn / 12, (pn / 4) % 3);
        }
    }

    // ---- epilogue: y = x + (acc + nv*b2)/3, then fused LayerNorm over D ----
    const float inv3 = 1.0f / 3.0f;
    const float fnv = (float)nv;
    float sum2[2] = {0.f, 0.f}, ssq2[2] = {0.f, 0.f};
    #pragma unroll
    for (int ri = 0; ri < 4; ri++) {
        #pragma unroll
        for (int ci = 0; ci < 2; ci++) {
            const int c = cols2[ci];
            #pragma unroll
            for (int t = 0; t < 4; t++) {
                const int dout = wm * 128 + ri * 32 + t * 8 + 4 * lh;
                const float4 bb = *reinterpret_cast<const float4*>(b2 + dout);
                const size_t xoff = ((size_t)b * L_ + c) * D_ + dout;
                const float4 xr = *reinterpret_cast<const float4*>(x + xoff);
                float y0 = xr.x + (acc[ri][ci][t * 4 + 0] + fnv * bb.x) * inv3;
                float y1 = xr.y + (acc[ri][ci][t * 4 + 1] + fnv * bb.y) * inv3;
                float y2 = xr.z + (acc[ri][ci][t * 4 + 2] + fnv * bb.z) * inv3;
                float y3 = xr.w + (acc[ri][ci][t * 4 + 3] + fnv * bb.w) * inv3;
                acc[ri][ci][t * 4 + 0] = y0;
                acc[ri][ci][t * 4 + 1] = y1;
                acc[ri][ci][t * 4 + 2] = y2;
                acc[ri][ci][t * 4 + 3] = y3;
                sum2[ci] += y0 + y1 + y2 + y3;
                ssq2[ci] += y0 * y0 + y1 * y1 + y2 * y2 + y3 * y3;
            }
        }
    }
    #pragma unroll
    for (int ci = 0; ci < 2; ci++) {
        sum2[ci] += __shfl_xor(sum2[ci], 32);
        ssq2[ci] += __shfl_xor(ssq2[ci], 32);
    }
    float* red = (float*)&sB[0][0];
    if (lh == 0) {
        #pragma unroll
        for (int ci = 0; ci < 2; ci++) {
            red[((w * 2 + ci) * 32 + l31) * 2 + 0] = sum2[ci];
            red[((w * 2 + ci) * 32 + l31) * 2 + 1] = ssq2[ci];
        }
    }
    __syncthreads();
    float muv[2], invv[2];
    #pragma unroll
    for (int ci = 0; ci < 2; ci++) {
        float ts = red[((wn * 2 + ci) * 32 + l31) * 2 + 0] +
                   red[(((2 + wn) * 2 + ci) * 32 + l31) * 2 + 0];
        float tq = red[((wn * 2 + ci) * 32 + l31) * 2 + 1] +
                   red[(((2 + wn) * 2 + ci) * 32 + l31) * 2 + 1];
        float mu = ts * (1.0f / 256.0f);
        float var = tq * (1.0f / 256.0f) - mu * mu;
        muv[ci] = mu;
        invv[ci] = 1.0f / sqrtf(var + 1e-5f);
    }
    #pragma unroll
    for (int ri = 0; ri < 4; ri++) {
        #pragma unroll
        for (int ci = 0; ci < 2; ci++) {
            const int c = cols2[ci];
            const float mu = muv[ci], inv = invv[ci];
            #pragma unroll
            for (int t = 0; t < 4; t++) {
                const int dout = wm * 128 + ri * 32 + t * 8 + 4 * lh;
                const float4 g4 = *reinterpret_cast<const float4*>(gamma + dout);
                const float4 be4 = *reinterpret_cast<const float4*>(beta + dout);
                const size_t xoff = ((size_t)b * L_ + c) * D_ + dout;
                float4 o;
                o.x = (acc[ri][ci][t * 4 + 0] - mu) * inv * g4.x + be4.x;
                o.y = (acc[ri][ci][t * 4 + 1] - mu) * inv * g4.y + be4.y;
                o.z = (acc[ri][ci][t * 4 + 2] - mu) * inv * g4.z + be4.z;
                o.w = (acc[ri][ci][t * 4 + 3] - mu) * inv * g4.w + be4.w;
                *reinterpret_cast<float4*>(yout + xoff) = o;
            }
        }
    }
}

extern "C" void kernel_launch(void* const* d_in, const int* in_sizes, int n_in,
                              void* d_out, int out_size, void* d_ws, size_t ws_size,
                              hipStream_t stream) {
    const float* x     = (const float*)d_in[0];
    const float* W1    = (const float*)d_in[1];
    const float* b1    = (const float*)d_in[2];
    const float* W2    = (const float*)d_in[3];
    const float* b2    = (const float*)d_in[4];
    const float* gamma = (const float*)d_in[5];
    const float* beta  = (const float*)d_in[6];
    float* out = (float*)d_out;

    char* ws = (char*)d_ws;
    size_t off = 0;
    auto walloc = [&](size_t bytes) -> void* {
        void* pp = ws + off;
        off += (bytes + 255) & ~(size_t)255;
        return pp;
    };
    unsigned short* xb    = (unsigned short*)walloc((size_t)B_ * L_ * D_ * 2);
    unsigned short* out1g = (unsigned short*)walloc((size_t)B_ * 3 * LPMAX * C_ * 2);
    float* series         = (float*)walloc((size_t)B_ * L_ * 4);
    float* mag2           = (float*)walloc((size_t)B_ * 513 * 4);
    int* periods          = (int*)walloc((size_t)B_ * 3 * 4);
    double* tw            = (double*)walloc(1024 * 16);
    unsigned short* W1s   = (unsigned short*)walloc((size_t)294912 * 2);
    unsigned short* W2s   = (unsigned short*)walloc((size_t)294912 * 2);

    prep_kernel<<<B_ * L_ / 4, 256, 0, stream>>>(x, xb, series);
    tw_kernel<<<4, 256, 0, stream>>>(tw);
    repack_kernel<<<2304, 256, 0, stream>>>(W1, W2, W1s, W2s);
    dft_kernel<<<(B_ * 513 + 3) / 4, 256, 0, stream>>>(series, tw, mag2);
    topk_kernel<<<B_, 64, 0, stream>>>(mag2, periods);
    conv1_kernel<<<B_ * 3 * 12, 256, 0, stream>>>(xb, W1s, b1, periods, out1g);
    conv2_kernel<<<B_ * 8, 256, 0, stream>>>(out1g, W2s, b2, periods, x, gamma, beta, out);
}

// Round 19
// 332.707 us; speedup vs baseline: 1.1973x; 1.0876x over previous
//
#include <hip/hip_runtime.h>
#include <hip/hip_bf16.h>
#include <math.h>

#define B_ 64
#define L_ 1024
#define D_ 256
#define C_ 128
#define LPMAX 1536

typedef __bf16 bf16x8 __attribute__((ext_vector_type(8)));
typedef float f32x16 __attribute__((ext_vector_type(16)));

__device__ __forceinline__ unsigned short f2bf(float f) {
    __hip_bfloat16 h = __float2bfloat16(f);
    return __builtin_bit_cast(unsigned short, h);
}

__device__ __forceinline__ float gelu_exact(float f) {
    return 0.5f * f * (1.0f + erff(f * 0.70710678118654752440f));
}

// async global->LDS: global src is per-lane, LDS dest = wave-uniform base + lane*16
__device__ __forceinline__ void gl16(const unsigned short* g, unsigned short* l) {
    __builtin_amdgcn_global_load_lds(
        (const __attribute__((address_space(1))) unsigned int*)g,
        (__attribute__((address_space(3))) unsigned int*)l, 16, 0, 0);
}

// ---- 1. cast x to bf16 + channel-mean series ----
__global__ void prep_kernel(const float* __restrict__ x, unsigned short* __restrict__ xb,
                            float* __restrict__ series) {
    int row = blockIdx.x * 4 + (threadIdx.x >> 6);
    int lane = threadIdx.x & 63;
    size_t base = (size_t)row * D_ + lane * 4;
    float4 v = *reinterpret_cast<const float4*>(x + base);
    ushort4 o;
    o.x = f2bf(v.x); o.y = f2bf(v.y); o.z = f2bf(v.z); o.w = f2bf(v.w);
    *reinterpret_cast<ushort4*>(xb + base) = o;
    float s = v.x + v.y + v.z + v.w;
    #pragma unroll
    for (int d = 32; d; d >>= 1) s += __shfl_xor(s, d);
    if (lane == 0) series[row] = s * (1.0f / D_);
}

// ---- 3. repack weights into per-phase LDS images (+ twiddle table in tail blocks) ----
// W1s: [tap(9)][kk(8)][rb(8)][q(4)][rr(16)][8]  (row=rb*16+rr in 0..127, d=kk*32+q*8+e)
// W2s: [tap(9)][kk(4)][rb(16)][q(4)][rr(16)][8] (row=rb*16+rr in 0..255, c=kk*32+q*8+e)
__global__ void repack_kernel(const float* __restrict__ W1, const float* __restrict__ W2,
                              unsigned short* __restrict__ W1s, unsigned short* __restrict__ W2s,
                              double* __restrict__ tw) {
    if (blockIdx.x >= 2304) {
        int j = (blockIdx.x - 2304) * 256 + threadIdx.x;
        if (j < 1024) {
            double a = -2.0 * 3.14159265358979323846 * (double)j / 1024.0;
            tw[2 * j] = cos(a);
            tw[2 * j + 1] = sin(a);
        }
        return;
    }
    int i = blockIdx.x * 256 + threadIdx.x;
    if (i < 294912) {
        int img = i >> 12;               // tap*8 + kk
        int tap = img >> 3, kk = img & 7;
        int within = i & 4095;
        int rb = within >> 9, q = (within >> 7) & 3, rr = (within >> 3) & 15, e = i & 7;
        int c = rb * 16 + rr, d = kk * 32 + q * 8 + e;
        int dt = tap / 3, dp = tap % 3;
        W1s[i] = f2bf(W1[((c * D_ + d) * 3 + dt) * 3 + dp]);
    } else {
        int i2 = i - 294912;
        if (i2 < 294912) {
            int img = i2 >> 13;          // tap*4 + kk
            int tap = img >> 2, kk = img & 3;
            int within = i2 & 8191;
            int rb = within >> 9, q = (within >> 7) & 3, rr = (within >> 3) & 15, e = i2 & 7;
            int dout = rb * 16 + rr, cin = kk * 32 + q * 8 + e;
            int dt = tap / 3, dp = tap % 3;
            W2s[i2] = f2bf(W2[((dout * C_ + cin) * 3 + dt) * 3 + dp]);
        }
    }
}

// ---- 4. DFT magnitude^2 (double, twiddle recurrence); 4 (b,k) pairs / 256-thr block ----
__global__ void dft_kernel(const float* __restrict__ series, const double* __restrict__ tw,
                           float* __restrict__ mag2) {
    int idx = blockIdx.x * 4 + (threadIdx.x >> 6);
    if (idx >= B_ * 513) return;
    int k = idx % 513, b = idx / 513;
    int lane = threadIdx.x & 63;
    const float* s = series + (size_t)b * L_;
    // initial twiddle e^{-2pi i k*lane/1024} (one gather) and the wave-uniform
    // step rotation e^{-2pi i k*64/1024} (scalar loads)
    int i0 = (k * lane) & 1023;
    double tr = tw[2 * i0], ti = tw[2 * i0 + 1];
    int ir = (k * 64) & 1023;
    double cr = tw[2 * ir], ci = tw[2 * ir + 1];
    double re = 0.0, im = 0.0;
    #pragma unroll
    for (int i = 0; i < 16; i++) {
        double sv = (double)s[lane + 64 * i];
        re += sv * tr;
        im += sv * ti;
        double nr = tr * cr - ti * ci;
        double ni = tr * ci + ti * cr;
        tr = nr; ti = ni;
    }
    #pragma unroll
    for (int d = 32; d; d >>= 1) { re += __shfl_down(re, d); im += __shfl_down(im, d); }
    if (lane == 0) mag2[idx] = (k == 0) ? 0.0f : (float)(re * re + im * im);
}

// ---- 5. top-3, wave-parallel argmax (tie -> lowest index) ----
__global__ void topk_kernel(const float* __restrict__ mag2, int* __restrict__ periods) {
    int b = blockIdx.x;
    int lane = threadIdx.x;
    const float* m = mag2 + b * 513;
    float v[9]; int kid[9];
    #pragma unroll
    for (int r = 0; r < 9; r++) {
        int k = r * 64 + lane;
        kid[r] = k;
        v[r] = (k < 513) ? m[k] : -1.0f;
    }
    int s0 = -1, s1 = -1;
    for (int j = 0; j < 3; j++) {
        float best = -1.0f; int bi = 0x7fffffff;
        #pragma unroll
        for (int r = 0; r < 9; r++) {
            bool skip = (kid[r] == s0) || (kid[r] == s1) || (kid[r] >= 513);
            if (!skip && (v[r] > best || (v[r] == best && kid[r] < bi))) { best = v[r]; bi = kid[r]; }
        }
        #pragma unroll
        for (int d = 32; d; d >>= 1) {
            float ov = __shfl_xor(best, d);
            int oi = __shfl_xor(bi, d);
            if (ov > best || (ov == best && oi < bi)) { best = ov; bi = oi; }
        }
        if (lane == 0) periods[b * 3 + j] = bi + 1;
        if (j == 0) s0 = bi; else if (j == 1) s1 = bi;
    }
}

// ---- 6. conv1 (256->128) + bias + GELU, output col-major bf16 ----
// r16 optimum: 128x128 tile, 32x32 MFMA, A single-buf gl16, B 10-slot dbuf,
// 46KB LDS -> 3 blk/CU, 24 phases x 24 MFMA.
__global__ __launch_bounds__(256, 3)
void conv1_kernel(const unsigned short* __restrict__ xb,
                  const unsigned short* __restrict__ W1s,
                  const float* __restrict__ b1,
                  const int* __restrict__ periods,
                  unsigned short* __restrict__ out1g) {
    __shared__ __align__(16) unsigned short sA[12288];     // [dp(3)][sub(8)][512] single buffer
    __shared__ __align__(16) unsigned short sB[2][5632];   // [slot(10)][512]; slot10=zeros

    const int blk = blockIdx.x;
    const int xcd = blk & 7;
    const int li = blk >> 3;            // 0..287
    const int b = xcd * 8 + li / 36;
    const int rem = li % 36;
    const int j = rem / 12, tile = rem % 12;

    const int p = periods[b * 3 + j];
    if (p <= 1) return;
    const int T = (L_ + p - 1) / p;
    const int Lp = T * p;
    const int col0 = tile * 128;
    if (col0 >= Lp) return;

    const int tid = threadIdx.x;
    const int w = tid >> 6, lane = tid & 63;
    const int wm = w >> 1, wn = w & 1;
    const int l15 = lane & 15, l4 = lane >> 4;
    const int l31 = lane & 31, lh = lane >> 5;
    const int s0w = (w < 2) ? w * 3 : 6 + (w - 2) * 2;   // B slot base per wave
    const int nsw = (w < 2) ? 3 : 2;                     // B slots per wave

    const unsigned short* xbb = xb + (size_t)b * L_ * D_;

    int cols2[2], ppv2[2], ttv2[2];
    #pragma unroll
    for (int ci = 0; ci < 2; ci++) {
        cols2[ci] = col0 + wn * 64 + ci * 32 + l31;
        ppv2[ci] = cols2[ci] % p;
        ttv2[ci] = cols2[ci] / p;
    }

    int arow32[2];
    #pragma unroll
    for (int ri = 0; ri < 2; ri++)
        arow32[ri] = (wm * 4 + ri * 2 + (l31 >> 4)) * 512 + lh * 128 + (l31 & 15) * 8;
    const int zoff32 = 10 * 512 + lh * 128 + (l31 & 15) * 8;

    f32x16 acc00 = {0.f}, acc01 = {0.f}, acc10 = {0.f}, acc11 = {0.f};

    // zero the redirect slot (slot 10, both buffers)
    {
        int bf = tid >> 7, r = tid & 127;
        ushort4 z = {0, 0, 0, 0};
        *reinterpret_cast<ushort4*>(&sB[bf][10 * 512 + r * 4]) = z;
    }

    int locv[3][2];
    auto setmask = [&](int dt) {
        #pragma unroll
        for (int dp = 0; dp < 3; dp++)
            #pragma unroll
            for (int ci = 0; ci < 2; ci++) {
                int pd = ppv2[ci] + dp, td = ttv2[ci] + dt;
                int t = cols2[ci] + (dt - 1) * p + dp - 1;
                bool ok = (pd >= 1) && (pd <= p) && (td >= 1) && (td <= T) &&
                          (cols2[ci] < Lp) && (t < L_);
                int rc = wn * 64 + ci * 32 + 15 + dp + l31;
                int off = (rc >> 4) * 512 + lh * 128 + (rc & 15) * 8;
                locv[dp][ci] = ok ? off : zoff32;
            }
    };

    const unsigned short* gaB[3];
    auto setaddrB = [&](int dt) {
        const int win1 = col0 + (dt - 1) * p - 16;
        #pragma unroll
        for (int i = 0; i < 3; i++) {
            int c = win1 + (s0w + i) * 16 + l15;
            c = c < 0 ? 0 : (c > L_ - 1 ? L_ - 1 : c);
            gaB[i] = xbb + (size_t)c * D_ + l4 * 8;
        }
    };

    auto stageB = [&](int buf, int kk) {
        unsigned short* lb = sB[buf];
        #pragma unroll
        for (int i = 0; i < 3; i++)
            if (i < nsw) gl16(gaB[i] + kk * 32, lb + (s0w + i) * 512);
    };

    auto stageA = [&](int dt, int kk) {
        #pragma unroll
        for (int s6 = 0; s6 < 6; s6++) {
            int pi = w * 6 + s6;
            int dp = pi >> 3, sub = pi & 7;
            gl16(W1s + (size_t)((dt * 3 + dp) * 8 + kk) * 4096 + sub * 512 + lane * 8,
                 sA + pi * 512);
        }
    };

    setmask(0);
    setaddrB(0);
    stageB(0, 0);
    stageA(0, 0);
    asm volatile("s_waitcnt lgkmcnt(0)" ::: "memory");

    for (int ph = 0; ph < 24; ph++) {
        const int cur = ph & 1;
        const int pn = ph + 1;
        asm volatile("s_waitcnt vmcnt(0)" ::: "memory");
        __builtin_amdgcn_s_barrier();
        __builtin_amdgcn_sched_barrier(0);
        if (pn < 24) {                       // B for next phase: ages under this MFMA phase
            if ((pn & 7) == 0) setaddrB(pn >> 3);
            stageB(cur ^ 1, pn & 7);
        }
        __builtin_amdgcn_sched_barrier(0);
        __builtin_amdgcn_s_setprio(1);
        {
            const unsigned short* lb = sB[cur];
            #pragma unroll
            for (int dp = 0; dp < 3; dp++) {
                #pragma unroll
                for (int ks = 0; ks < 2; ks++) {
                    bf16x8 Af0 = *reinterpret_cast<const bf16x8*>(sA + dp * 4096 + arow32[0] + ks * 256);
                    bf16x8 Af1 = *reinterpret_cast<const bf16x8*>(sA + dp * 4096 + arow32[1] + ks * 256);
                    bf16x8 Bf0 = *reinterpret_cast<const bf16x8*>(lb + locv[dp][0] + ks * 256);
                    bf16x8 Bf1 = *reinterpret_cast<const bf16x8*>(lb + locv[dp][1] + ks * 256);
                    acc00 = __builtin_amdgcn_mfma_f32_32x32x16_bf16(Af0, Bf0, acc00, 0, 0, 0);
                    acc01 = __builtin_amdgcn_mfma_f32_32x32x16_bf16(Af0, Bf1, acc01, 0, 0, 0);
                    acc10 = __builtin_amdgcn_mfma_f32_32x32x16_bf16(Af1, Bf0, acc10, 0, 0, 0);
                    acc11 = __builtin_amdgcn_mfma_f32_32x32x16_bf16(Af1, Bf1, acc11, 0, 0, 0);
                }
            }
        }
        __builtin_amdgcn_s_setprio(0);
        asm volatile("s_waitcnt lgkmcnt(0)" ::: "memory");   // my sA ds_reads retired
        __builtin_amdgcn_sched_barrier(0);
        __builtin_amdgcn_s_barrier();                        // all waves done reading sA
        if (pn < 24) {
            stageA(pn >> 3, pn & 7);
            if ((pn & 7) == 0) setmask(pn >> 3);
        }
    }

    const size_t ob = (size_t)(b * 3 + j) * LPMAX * C_;
    const f32x16* accs[4] = { &acc00, &acc01, &acc10, &acc11 };
    #pragma unroll
    for (int ri = 0; ri < 2; ri++) {
        #pragma unroll
        for (int ci = 0; ci < 2; ci++) {
            const f32x16& a = *accs[ri * 2 + ci];
            const int c = cols2[ci];
            if (c < Lp) {
                #pragma unroll
                for (int t = 0; t < 4; t++) {
                    const int ch = wm * 64 + ri * 32 + t * 8 + 4 * lh;
                    const float4 bias = *reinterpret_cast<const float4*>(b1 + ch);
                    ushort4 o;
                    o.x = f2bf(gelu_exact(a[t * 4 + 0] + bias.x));
                    o.y = f2bf(gelu_exact(a[t * 4 + 1] + bias.y));
                    o.z = f2bf(gelu_exact(a[t * 4 + 2] + bias.z));
                    o.w = f2bf(gelu_exact(a[t * 4 + 3] + bias.w));
                    *reinterpret_cast<ushort4*>(out1g + ob + (size_t)c * C_ + ch) = o;
                }
            }
        }
    }
}

// ---- 7. conv2 (128->256) + residual + FUSED LayerNorm; writes final out ----
__global__ __launch_bounds__(256, 2)
void conv2_kernel(const unsigned short* __restrict__ out1g,
                  const unsigned short* __restrict__ W2s,
                  const float* __restrict__ b2,
                  const int* __restrict__ periods,
                  const float* __restrict__ x,
                  const float* __restrict__ gamma,
                  const float* __restrict__ beta,
                  float* __restrict__ yout) {
    __shared__ __align__(16) unsigned short sA[24576];     // [dp(3)][rb(16)][512]
    __shared__ __align__(16) unsigned short sB[2][5632];   // [slot(10)+zero][512]

    const int blk = blockIdx.x;
    const int xcd = blk & 7;
    const int li = blk >> 3;            // 0..63
    const int b = xcd * 8 + (li >> 3);
    const int tile = li & 7;
    const int col0 = tile * 128;

    const int tid = threadIdx.x;
    const int w = tid >> 6, lane = tid & 63;
    const int wm = w >> 1, wn = w & 1;
    const int l15 = lane & 15, l4 = lane >> 4;
    const int l31 = lane & 31, lh = lane >> 5;
    const int s0w = (w < 2) ? w * 3 : 6 + (w - 2) * 2;
    const int nsw = (w < 2) ? 3 : 2;
    const int wcol = wn * 64;

    int p_all[3];
    #pragma unroll
    for (int jj = 0; jj < 3; jj++) p_all[jj] = periods[b * 3 + jj];
    const int nv = (p_all[0] > 1) + (p_all[1] > 1) + (p_all[2] > 1);

    int cols2[2];
    #pragma unroll
    for (int ci = 0; ci < 2; ci++) cols2[ci] = col0 + wcol + ci * 32 + l31;

    int arow32[4];
    #pragma unroll
    for (int ri = 0; ri < 4; ri++)
        arow32[ri] = (wm * 8 + ri * 2 + (l31 >> 4)) * 512 + lh * 128 + (l31 & 15) * 8;
    const int zoff32 = 10 * 512 + lh * 128 + (l31 & 15) * 8;

    f32x16 acc[4][2];
    #pragma unroll
    for (int ri = 0; ri < 4; ri++)
        #pragma unroll
        for (int ci = 0; ci < 2; ci++)
            acc[ri][ci] = f32x16{0.f};

    {
        int bf = tid >> 7, r = tid & 127;
        ushort4 z = {0, 0, 0, 0};
        *reinterpret_cast<ushort4*>(&sB[bf][10 * 512 + r * 4]) = z;
    }

    int locv[3][2];
    auto setmask = [&](int jn, int dt) {
        const int pj = p_all[jn];
        const int Tj = (L_ + pj - 1) / pj;
        const bool okj = pj > 1;
        #pragma unroll
        for (int dp = 0; dp < 3; dp++)
            #pragma unroll
            for (int ci = 0; ci < 2; ci++) {
                int pv = cols2[ci] % pj, tv = cols2[ci] / pj;
                int pd = pv + dp, td = tv + dt;
                bool ok = okj && (pd >= 1) && (pd <= pj) && (td >= 1) && (td <= Tj);
                int rc = wcol + ci * 32 + 15 + dp + l31;
                int off = (rc >> 4) * 512 + lh * 128 + (rc & 15) * 8;
                locv[dp][ci] = ok ? off : zoff32;
            }
    };

    const unsigned short* gaB[3];
    auto setaddrB = [&](int jn, int dt) {
        const int pj = p_all[jn];
        const unsigned short* bbj = out1g + (size_t)(b * 3 + jn) * LPMAX * C_;
        const int win1 = col0 + (dt - 1) * pj - 16;
        #pragma unroll
        for (int i = 0; i < 3; i++) {
            int c = win1 + (s0w + i) * 16 + l15;
            c = c < 0 ? 0 : (c > LPMAX - 1 ? LPMAX - 1 : c);
            gaB[i] = bbj + (size_t)c * C_ + l4 * 8;
        }
    };

    auto stageB = [&](int buf, int kk) {
        unsigned short* lb = sB[buf];
        #pragma unroll
        for (int i = 0; i < 3; i++)
            if (i < nsw) gl16(gaB[i] + kk * 32, lb + (s0w + i) * 512);
    };

    auto stageA = [&](int dt, int kk) {
        #pragma unroll
        for (int s12 = 0; s12 < 12; s12++) {
            int pi = w * 12 + s12;
            int dp = pi >> 4, sub = pi & 15;
            gl16(W2s + (size_t)((dt * 3 + dp) * 4 + kk) * 8192 + sub * 512 + lane * 8,
                 sA + pi * 512);
        }
    };

    setmask(0, 0);
    setaddrB(0, 0);
    stageB(0, 0);
    stageA(0, 0);

    for (int ph = 0; ph < 36; ph++) {
        const int cur = ph & 1;
        const int pn = ph + 1;
        asm volatile("s_waitcnt vmcnt(0)" ::: "memory");
        __builtin_amdgcn_s_barrier();
        __builtin_amdgcn_sched_barrier(0);
        if (pn < 36) {
            if ((pn & 3) == 0) setaddrB(pn / 12, (pn / 4) % 3);
            stageB(cur ^ 1, pn & 3);
        }
        __builtin_amdgcn_sched_barrier(0);
        __builtin_amdgcn_s_setprio(1);
        {
            const unsigned short* lb = sB[cur];
            #pragma unroll
            for (int dp = 0; dp < 3; dp++) {
                #pragma unroll
                for (int ks = 0; ks < 2; ks++) {
                    bf16x8 Bf0 = *reinterpret_cast<const bf16x8*>(lb + locv[dp][0] + ks * 256);
                    bf16x8 Bf1 = *reinterpret_cast<const bf16x8*>(lb + locv[dp][1] + ks * 256);
                    #pragma unroll
                    for (int ri = 0; ri < 4; ri++) {
                        bf16x8 Af = *reinterpret_cast<const bf16x8*>(sA + dp * 8192 + arow32[ri] + ks * 256);
                        acc[ri][0] = __builtin_amdgcn_mfma_f32_32x32x16_bf16(Af, Bf0, acc[ri][0], 0, 0, 0);
                        acc[ri][1] = __builtin_amdgcn_mfma_f32_32x32x16_bf16(Af, Bf1, acc[ri][1], 0, 0, 0);
                    }
                }
            }
        }
        __builtin_amdgcn_s_setprio(0);
        asm volatile("s_waitcnt lgkmcnt(0)" ::: "memory");
        __builtin_amdgcn_sched_barrier(0);
        __builtin_amdgcn_s_barrier();
        if (pn < 36) {
            stageA((pn / 4) % 3, pn & 3);
            if ((pn & 3) == 0) setmask(pn / 12, (pn / 4) % 3);
        }
    }

    // ---- epilogue: y = x + (acc + nv*b2)/3, then fused LayerNorm over D ----
    const float inv3 = 1.0f / 3.0f;
    const float fnv = (float)nv;
    float sum2[2] = {0.f, 0.f}, ssq2[2] = {0.f, 0.f};
    #pragma unroll
    for (int ri = 0; ri < 4; ri++) {
        #pragma unroll
        for (int ci = 0; ci < 2; ci++) {
            const int c = cols2[ci];
            #pragma unroll
            for (int t = 0; t < 4; t++) {
                const int dout = wm * 128 + ri * 32 + t * 8 + 4 * lh;
                const float4 bb = *reinterpret_cast<const float4*>(b2 + dout);
                const size_t xoff = ((size_t)b * L_ + c) * D_ + dout;
                const float4 xr = *reinterpret_cast<const float4*>(x + xoff);
                float y0 = xr.x + (acc[ri][ci][t * 4 + 0] + fnv * bb.x) * inv3;
                float y1 = xr.y + (acc[ri][ci][t * 4 + 1] + fnv * bb.y) * inv3;
                float y2 = xr.z + (acc[ri][ci][t * 4 + 2] + fnv * bb.z) * inv3;
                float y3 = xr.w + (acc[ri][ci][t * 4 + 3] + fnv * bb.w) * inv3;
                acc[ri][ci][t * 4 + 0] = y0;
                acc[ri][ci][t * 4 + 1] = y1;
                acc[ri][ci][t * 4 + 2] = y2;
                acc[ri][ci][t * 4 + 3] = y3;
                sum2[ci] += y0 + y1 + y2 + y3;
                ssq2[ci] += y0 * y0 + y1 * y1 + y2 * y2 + y3 * y3;
            }
        }
    }
    #pragma unroll
    for (int ci = 0; ci < 2; ci++) {
        sum2[ci] += __shfl_xor(sum2[ci], 32);
        ssq2[ci] += __shfl_xor(ssq2[ci], 32);
    }
    float* red = (float*)&sB[0][0];
    if (lh == 0) {
        #pragma unroll
        for (int ci = 0; ci < 2; ci++) {
            red[((w * 2 + ci) * 32 + l31) * 2 + 0] = sum2[ci];
            red[((w * 2 + ci) * 32 + l31) * 2 + 1] = ssq2[ci];
        }
    }
    __syncthreads();
    float muv[2], invv[2];
    #pragma unroll
    for (int ci = 0; ci < 2; ci++) {
        float ts = red[((wn * 2 + ci) * 32 + l31) * 2 + 0] +
                   red[(((2 + wn) * 2 + ci) * 32 + l31) * 2 + 0];
        float tq = red[((wn * 2 + ci) * 32 + l31) * 2 + 1] +
                   red[(((2 + wn) * 2 + ci) * 32 + l31) * 2 + 1];
        float mu = ts * (1.0f / 256.0f);
        float var = tq * (1.0f / 256.0f) - mu * mu;
        muv[ci] = mu;
        invv[ci] = 1.0f / sqrtf(var + 1e-5f);
    }
    #pragma unroll
    for (int ri = 0; ri < 4; ri++) {
        #pragma unroll
        for (int ci = 0; ci < 2; ci++) {
            const int c = cols2[ci];
            const float mu = muv[ci], inv = invv[ci];
            #pragma unroll
            for (int t = 0; t < 4; t++) {
                const int dout = wm * 128 + ri * 32 + t * 8 + 4 * lh;
                const float4 g4 = *reinterpret_cast<const float4*>(gamma + dout);
                const float4 be4 = *reinterpret_cast<const float4*>(beta + dout);
                const size_t xoff = ((size_t)b * L_ + c) * D_ + dout;
                float4 o;
                o.x = (acc[ri][ci][t * 4 + 0] - mu) * inv * g4.x + be4.x;
                o.y = (acc[ri][ci][t * 4 + 1] - mu) * inv * g4.y + be4.y;
                o.z = (acc[ri][ci][t * 4 + 2] - mu) * inv * g4.z + be4.z;
                o.w = (acc[ri][ci][t * 4 + 3] - mu) * inv * g4.w + be4.w;
                *reinterpret_cast<float4*>(yout + xoff) = o;
            }
        }
    }
}

extern "C" void kernel_launch(void* const* d_in, const int* in_sizes, int n_in,
                              void* d_out, int out_size, void* d_ws, size_t ws_size,
                              hipStream_t stream) {
    const float* x     = (const float*)d_in[0];
    const float* W1    = (const float*)d_in[1];
    const float* b1    = (const float*)d_in[2];
    const float* W2    = (const float*)d_in[3];
    const float* b2    = (const float*)d_in[4];
    const float* gamma = (const float*)d_in[5];
    const float* beta  = (const float*)d_in[6];
    float* out = (float*)d_out;

    char* ws = (char*)d_ws;
    size_t off = 0;
    auto walloc = [&](size_t bytes) -> void* {
        void* pp = ws + off;
        off += (bytes + 255) & ~(size_t)255;
        return pp;
    };
    unsigned short* xb    = (unsigned short*)walloc((size_t)B_ * L_ * D_ * 2);
    unsigned short* out1g = (unsigned short*)walloc((size_t)B_ * 3 * LPMAX * C_ * 2);
    float* series         = (float*)walloc((size_t)B_ * L_ * 4);
    float* mag2           = (float*)walloc((size_t)B_ * 513 * 4);
    int* periods          = (int*)walloc((size_t)B_ * 3 * 4);
    double* tw            = (double*)walloc(1024 * 16);
    unsigned short* W1s   = (unsigned short*)walloc((size_t)294912 * 2);
    unsigned short* W2s   = (unsigned short*)walloc((size_t)294912 * 2);

    prep_kernel<<<B_ * L_ / 4, 256, 0, stream>>>(x, xb, series);
    repack_kernel<<<2308, 256, 0, stream>>>(W1, W2, W1s, W2s, tw);
    dft_kernel<<<(B_ * 513 + 3) / 4, 256, 0, stream>>>(series, tw, mag2);
    topk_kernel<<<B_, 64, 0, stream>>>(mag2, periods);
    conv1_kernel<<<B_ * 3 * 12, 256, 0, stream>>>(xb, W1s, b1, periods, out1g);
    conv2_kernel<<<B_ * 8, 256, 0, stream>>>(out1g, W2s, b2, periods, x, gamma, beta, out);
}

// Round 20
// 332.180 us; speedup vs baseline: 1.1992x; 1.0016x over previous
//
#include <hip/hip_runtime.h>
#include <hip/hip_bf16.h>
#include <math.h>

#define B_ 64
#define L_ 1024
#define D_ 256
#define C_ 128
#define LPMAX 1536

typedef __bf16 bf16x8 __attribute__((ext_vector_type(8)));
typedef float f32x16 __attribute__((ext_vector_type(16)));

__device__ __forceinline__ unsigned short f2bf(float f) {
    __hip_bfloat16 h = __float2bfloat16(f);
    return __builtin_bit_cast(unsigned short, h);
}

__device__ __forceinline__ float bf2f(unsigned short u) {
    unsigned int x = ((unsigned int)u) << 16;
    return __builtin_bit_cast(float, x);
}

__device__ __forceinline__ float gelu_exact(float f) {
    return 0.5f * f * (1.0f + erff(f * 0.70710678118654752440f));
}

// async global->LDS: global src is per-lane, LDS dest = wave-uniform base + lane*16
__device__ __forceinline__ void gl16(const unsigned short* g, unsigned short* l) {
    __builtin_amdgcn_global_load_lds(
        (const __attribute__((address_space(1))) unsigned int*)g,
        (__attribute__((address_space(3))) unsigned int*)l, 16, 0, 0);
}

// ---- 1. cast x to bf16 + channel-mean series ----
__global__ void prep_kernel(const float* __restrict__ x, unsigned short* __restrict__ xb,
                            float* __restrict__ series) {
    int row = blockIdx.x * 4 + (threadIdx.x >> 6);
    int lane = threadIdx.x & 63;
    size_t base = (size_t)row * D_ + lane * 4;
    float4 v = *reinterpret_cast<const float4*>(x + base);
    ushort4 o;
    o.x = f2bf(v.x); o.y = f2bf(v.y); o.z = f2bf(v.z); o.w = f2bf(v.w);
    *reinterpret_cast<ushort4*>(xb + base) = o;
    float s = v.x + v.y + v.z + v.w;
    #pragma unroll
    for (int d = 32; d; d >>= 1) s += __shfl_xor(s, d);
    if (lane == 0) series[row] = s * (1.0f / D_);
}

// ---- 3. repack weights into per-phase LDS images (+ twiddle table in tail blocks) ----
// W1s: [tap(9)][kk(8)][rb(8)][q(4)][rr(16)][8]  (row=rb*16+rr in 0..127, d=kk*32+q*8+e)
// W2s: [tap(9)][kk(4)][rb(16)][q(4)][rr(16)][8] (row=rb*16+rr in 0..255, c=kk*32+q*8+e)
__global__ void repack_kernel(const float* __restrict__ W1, const float* __restrict__ W2,
                              unsigned short* __restrict__ W1s, unsigned short* __restrict__ W2s,
                              double* __restrict__ tw) {
    if (blockIdx.x >= 2304) {
        int j = (blockIdx.x - 2304) * 256 + threadIdx.x;
        if (j < 1024) {
            double a = -2.0 * 3.14159265358979323846 * (double)j / 1024.0;
            tw[2 * j] = cos(a);
            tw[2 * j + 1] = sin(a);
        }
        return;
    }
    int i = blockIdx.x * 256 + threadIdx.x;
    if (i < 294912) {
        int img = i >> 12;               // tap*8 + kk
        int tap = img >> 3, kk = img & 7;
        int within = i & 4095;
        int rb = within >> 9, q = (within >> 7) & 3, rr = (within >> 3) & 15, e = i & 7;
        int c = rb * 16 + rr, d = kk * 32 + q * 8 + e;
        int dt = tap / 3, dp = tap % 3;
        W1s[i] = f2bf(W1[((c * D_ + d) * 3 + dt) * 3 + dp]);
    } else {
        int i2 = i - 294912;
        if (i2 < 294912) {
            int img = i2 >> 13;          // tap*4 + kk
            int tap = img >> 2, kk = img & 3;
            int within = i2 & 8191;
            int rb = within >> 9, q = (within >> 7) & 3, rr = (within >> 3) & 15, e = i2 & 7;
            int dout = rb * 16 + rr, cin = kk * 32 + q * 8 + e;
            int dt = tap / 3, dp = tap % 3;
            W2s[i2] = f2bf(W2[((dout * C_ + cin) * 3 + dt) * 3 + dp]);
        }
    }
}

// ---- 4. DFT magnitude^2 (double, twiddle recurrence); 4 (b,k) pairs / 256-thr block ----
__global__ void dft_kernel(const float* __restrict__ series, const double* __restrict__ tw,
                           float* __restrict__ mag2) {
    int idx = blockIdx.x * 4 + (threadIdx.x >> 6);
    if (idx >= B_ * 513) return;
    int k = idx % 513, b = idx / 513;
    int lane = threadIdx.x & 63;
    const float* s = series + (size_t)b * L_;
    int i0 = (k * lane) & 1023;
    double tr = tw[2 * i0], ti = tw[2 * i0 + 1];
    int ir = (k * 64) & 1023;
    double cr = tw[2 * ir], ci = tw[2 * ir + 1];
    double re = 0.0, im = 0.0;
    #pragma unroll
    for (int i = 0; i < 16; i++) {
        double sv = (double)s[lane + 64 * i];
        re += sv * tr;
        im += sv * ti;
        double nr = tr * cr - ti * ci;
        double ni = tr * ci + ti * cr;
        tr = nr; ti = ni;
    }
    #pragma unroll
    for (int d = 32; d; d >>= 1) { re += __shfl_down(re, d); im += __shfl_down(im, d); }
    if (lane == 0) mag2[idx] = (k == 0) ? 0.0f : (float)(re * re + im * im);
}

// ---- 5. top-3, wave-parallel argmax (tie -> lowest index) ----
__global__ void topk_kernel(const float* __restrict__ mag2, int* __restrict__ periods) {
    int b = blockIdx.x;
    int lane = threadIdx.x;
    const float* m = mag2 + b * 513;
    float v[9]; int kid[9];
    #pragma unroll
    for (int r = 0; r < 9; r++) {
        int k = r * 64 + lane;
        kid[r] = k;
        v[r] = (k < 513) ? m[k] : -1.0f;
    }
    int s0 = -1, s1 = -1;
    for (int j = 0; j < 3; j++) {
        float best = -1.0f; int bi = 0x7fffffff;
        #pragma unroll
        for (int r = 0; r < 9; r++) {
            bool skip = (kid[r] == s0) || (kid[r] == s1) || (kid[r] >= 513);
            if (!skip && (v[r] > best || (v[r] == best && kid[r] < bi))) { best = v[r]; bi = kid[r]; }
        }
        #pragma unroll
        for (int d = 32; d; d >>= 1) {
            float ov = __shfl_xor(best, d);
            int oi = __shfl_xor(bi, d);
            if (ov > best || (ov == best && oi < bi)) { best = ov; bi = oi; }
        }
        if (lane == 0) periods[b * 3 + j] = bi + 1;
        if (j == 0) s0 = bi; else if (j == 1) s1 = bi;
    }
}

// ---- 6. conv1 (256->128) + bias + GELU, output col-major bf16 ----
// r16 optimum: 128x128 tile, 32x32 MFMA, A single-buf gl16, B 10-slot dbuf,
// 46KB LDS -> 3 blk/CU, 24 phases x 24 MFMA.
__global__ __launch_bounds__(256, 3)
void conv1_kernel(const unsigned short* __restrict__ xb,
                  const unsigned short* __restrict__ W1s,
                  const float* __restrict__ b1,
                  const int* __restrict__ periods,
                  unsigned short* __restrict__ out1g) {
    __shared__ __align__(16) unsigned short sA[12288];     // [dp(3)][sub(8)][512] single buffer
    __shared__ __align__(16) unsigned short sB[2][5632];   // [slot(10)][512]; slot10=zeros

    const int blk = blockIdx.x;
    const int xcd = blk & 7;
    const int li = blk >> 3;            // 0..287
    const int b = xcd * 8 + li / 36;
    const int rem = li % 36;
    const int j = rem / 12, tile = rem % 12;

    const int p = periods[b * 3 + j];
    if (p <= 1) return;
    const int T = (L_ + p - 1) / p;
    const int Lp = T * p;
    const int col0 = tile * 128;
    if (col0 >= Lp) return;

    const int tid = threadIdx.x;
    const int w = tid >> 6, lane = tid & 63;
    const int wm = w >> 1, wn = w & 1;
    const int l15 = lane & 15, l4 = lane >> 4;
    const int l31 = lane & 31, lh = lane >> 5;
    const int s0w = (w < 2) ? w * 3 : 6 + (w - 2) * 2;   // B slot base per wave
    const int nsw = (w < 2) ? 3 : 2;                     // B slots per wave

    const unsigned short* xbb = xb + (size_t)b * L_ * D_;

    int cols2[2], ppv2[2], ttv2[2];
    #pragma unroll
    for (int ci = 0; ci < 2; ci++) {
        cols2[ci] = col0 + wn * 64 + ci * 32 + l31;
        ppv2[ci] = cols2[ci] % p;
        ttv2[ci] = cols2[ci] / p;
    }

    int arow32[2];
    #pragma unroll
    for (int ri = 0; ri < 2; ri++)
        arow32[ri] = (wm * 4 + ri * 2 + (l31 >> 4)) * 512 + lh * 128 + (l31 & 15) * 8;
    const int zoff32 = 10 * 512 + lh * 128 + (l31 & 15) * 8;

    f32x16 acc00 = {0.f}, acc01 = {0.f}, acc10 = {0.f}, acc11 = {0.f};

    // zero the redirect slot (slot 10, both buffers)
    {
        int bf = tid >> 7, r = tid & 127;
        ushort4 z = {0, 0, 0, 0};
        *reinterpret_cast<ushort4*>(&sB[bf][10 * 512 + r * 4]) = z;
    }

    int locv[3][2];
    auto setmask = [&](int dt) {
        #pragma unroll
        for (int dp = 0; dp < 3; dp++)
            #pragma unroll
            for (int ci = 0; ci < 2; ci++) {
                int pd = ppv2[ci] + dp, td = ttv2[ci] + dt;
                int t = cols2[ci] + (dt - 1) * p + dp - 1;
                bool ok = (pd >= 1) && (pd <= p) && (td >= 1) && (td <= T) &&
                          (cols2[ci] < Lp) && (t < L_);
                int rc = wn * 64 + ci * 32 + 15 + dp + l31;
                int off = (rc >> 4) * 512 + lh * 128 + (rc & 15) * 8;
                locv[dp][ci] = ok ? off : zoff32;
            }
    };

    const unsigned short* gaB[3];
    auto setaddrB = [&](int dt) {
        const int win1 = col0 + (dt - 1) * p - 16;
        #pragma unroll
        for (int i = 0; i < 3; i++) {
            int c = win1 + (s0w + i) * 16 + l15;
            c = c < 0 ? 0 : (c > L_ - 1 ? L_ - 1 : c);
            gaB[i] = xbb + (size_t)c * D_ + l4 * 8;
        }
    };

    auto stageB = [&](int buf, int kk) {
        unsigned short* lb = sB[buf];
        #pragma unroll
        for (int i = 0; i < 3; i++)
            if (i < nsw) gl16(gaB[i] + kk * 32, lb + (s0w + i) * 512);
    };

    auto stageA = [&](int dt, int kk) {
        #pragma unroll
        for (int s6 = 0; s6 < 6; s6++) {
            int pi = w * 6 + s6;
            int dp = pi >> 3, sub = pi & 7;
            gl16(W1s + (size_t)((dt * 3 + dp) * 8 + kk) * 4096 + sub * 512 + lane * 8,
                 sA + pi * 512);
        }
    };

    setmask(0);
    setaddrB(0);
    stageB(0, 0);
    stageA(0, 0);
    asm volatile("s_waitcnt lgkmcnt(0)" ::: "memory");

    for (int ph = 0; ph < 24; ph++) {
        const int cur = ph & 1;
        const int pn = ph + 1;
        asm volatile("s_waitcnt vmcnt(0)" ::: "memory");
        __builtin_amdgcn_s_barrier();
        __builtin_amdgcn_sched_barrier(0);
        if (pn < 24) {                       // B for next phase: ages under this MFMA phase
            if ((pn & 7) == 0) setaddrB(pn >> 3);
            stageB(cur ^ 1, pn & 7);
        }
        __builtin_amdgcn_sched_barrier(0);
        __builtin_amdgcn_s_setprio(1);
        {
            const unsigned short* lb = sB[cur];
            #pragma unroll
            for (int dp = 0; dp < 3; dp++) {
                #pragma unroll
                for (int ks = 0; ks < 2; ks++) {
                    bf16x8 Af0 = *reinterpret_cast<const bf16x8*>(sA + dp * 4096 + arow32[0] + ks * 256);
                    bf16x8 Af1 = *reinterpret_cast<const bf16x8*>(sA + dp * 4096 + arow32[1] + ks * 256);
                    bf16x8 Bf0 = *reinterpret_cast<const bf16x8*>(lb + locv[dp][0] + ks * 256);
                    bf16x8 Bf1 = *reinterpret_cast<const bf16x8*>(lb + locv[dp][1] + ks * 256);
                    acc00 = __builtin_amdgcn_mfma_f32_32x32x16_bf16(Af0, Bf0, acc00, 0, 0, 0);
                    acc01 = __builtin_amdgcn_mfma_f32_32x32x16_bf16(Af0, Bf1, acc01, 0, 0, 0);
                    acc10 = __builtin_amdgcn_mfma_f32_32x32x16_bf16(Af1, Bf0, acc10, 0, 0, 0);
                    acc11 = __builtin_amdgcn_mfma_f32_32x32x16_bf16(Af1, Bf1, acc11, 0, 0, 0);
                }
            }
        }
        __builtin_amdgcn_s_setprio(0);
        asm volatile("s_waitcnt lgkmcnt(0)" ::: "memory");   // my sA ds_reads retired
        __builtin_amdgcn_sched_barrier(0);
        __builtin_amdgcn_s_barrier();                        // all waves done reading sA
        if (pn < 24) {
            stageA(pn >> 3, pn & 7);
            if ((pn & 7) == 0) setmask(pn >> 3);
        }
    }

    const size_t ob = (size_t)(b * 3 + j) * LPMAX * C_;
    const f32x16* accs[4] = { &acc00, &acc01, &acc10, &acc11 };
    #pragma unroll
    for (int ri = 0; ri < 2; ri++) {
        #pragma unroll
        for (int ci = 0; ci < 2; ci++) {
            const f32x16& a = *accs[ri * 2 + ci];
            const int c = cols2[ci];
            if (c < Lp) {
                #pragma unroll
                for (int t = 0; t < 4; t++) {
                    const int ch = wm * 64 + ri * 32 + t * 8 + 4 * lh;
                    const float4 bias = *reinterpret_cast<const float4*>(b1 + ch);
                    ushort4 o;
                    o.x = f2bf(gelu_exact(a[t * 4 + 0] + bias.x));
                    o.y = f2bf(gelu_exact(a[t * 4 + 1] + bias.y));
                    o.z = f2bf(gelu_exact(a[t * 4 + 2] + bias.z));
                    o.w = f2bf(gelu_exact(a[t * 4 + 3] + bias.w));
                    *reinterpret_cast<ushort4*>(out1g + ob + (size_t)c * C_ + ch) = o;
                }
            }
        }
    }
}

// ---- 7. conv2 (128->256) + residual(bf16 x) + FUSED LayerNorm; writes final out ----
__global__ __launch_bounds__(256, 2)
void conv2_kernel(const unsigned short* __restrict__ out1g,
                  const unsigned short* __restrict__ W2s,
                  const float* __restrict__ b2,
                  const int* __restrict__ periods,
                  const unsigned short* __restrict__ xb,
                  const float* __restrict__ gamma,
                  const float* __restrict__ beta,
                  float* __restrict__ yout) {
    __shared__ __align__(16) unsigned short sA[24576];     // [dp(3)][rb(16)][512]
    __shared__ __align__(16) unsigned short sB[2][5632];   // [slot(10)+zero][512]

    const int blk = blockIdx.x;
    const int xcd = blk & 7;
    const int li = blk >> 3;            // 0..63
    const int b = xcd * 8 + (li >> 3);
    const int tile = li & 7;
    const int col0 = tile * 128;

    const int tid = threadIdx.x;
    const int w = tid >> 6, lane = tid & 63;
    const int wm = w >> 1, wn = w & 1;
    const int l15 = lane & 15, l4 = lane >> 4;
    const int l31 = lane & 31, lh = lane >> 5;
    const int s0w = (w < 2) ? w * 3 : 6 + (w - 2) * 2;
    const int nsw = (w < 2) ? 3 : 2;
    const int wcol = wn * 64;

    int p_all[3];
    #pragma unroll
    for (int jj = 0; jj < 3; jj++) p_all[jj] = periods[b * 3 + jj];
    const int nv = (p_all[0] > 1) + (p_all[1] > 1) + (p_all[2] > 1);

    int cols2[2];
    #pragma unroll
    for (int ci = 0; ci < 2; ci++) cols2[ci] = col0 + wcol + ci * 32 + l31;

    int arow32[4];
    #pragma unroll
    for (int ri = 0; ri < 4; ri++)
        arow32[ri] = (wm * 8 + ri * 2 + (l31 >> 4)) * 512 + lh * 128 + (l31 & 15) * 8;
    const int zoff32 = 10 * 512 + lh * 128 + (l31 & 15) * 8;

    f32x16 acc[4][2];
    #pragma unroll
    for (int ri = 0; ri < 4; ri++)
        #pragma unroll
        for (int ci = 0; ci < 2; ci++)
            acc[ri][ci] = f32x16{0.f};

    {
        int bf = tid >> 7, r = tid & 127;
        ushort4 z = {0, 0, 0, 0};
        *reinterpret_cast<ushort4*>(&sB[bf][10 * 512 + r * 4]) = z;
    }

    int locv[3][2];
    auto setmask = [&](int jn, int dt) {
        const int pj = p_all[jn];
        const int Tj = (L_ + pj - 1) / pj;
        const bool okj = pj > 1;
        #pragma unroll
        for (int dp = 0; dp < 3; dp++)
            #pragma unroll
            for (int ci = 0; ci < 2; ci++) {
                int pv = cols2[ci] % pj, tv = cols2[ci] / pj;
                int pd = pv + dp, td = tv + dt;
                bool ok = okj && (pd >= 1) && (pd <= pj) && (td >= 1) && (td <= Tj);
                int rc = wcol + ci * 32 + 15 + dp + l31;
                int off = (rc >> 4) * 512 + lh * 128 + (rc & 15) * 8;
                locv[dp][ci] = ok ? off : zoff32;
            }
    };

    const unsigned short* gaB[3];
    auto setaddrB = [&](int jn, int dt) {
        const int pj = p_all[jn];
        const unsigned short* bbj = out1g + (size_t)(b * 3 + jn) * LPMAX * C_;
        const int win1 = col0 + (dt - 1) * pj - 16;
        #pragma unroll
        for (int i = 0; i < 3; i++) {
            int c = win1 + (s0w + i) * 16 + l15;
            c = c < 0 ? 0 : (c > LPMAX - 1 ? LPMAX - 1 : c);
            gaB[i] = bbj + (size_t)c * C_ + l4 * 8;
        }
    };

    auto stageB = [&](int buf, int kk) {
        unsigned short* lb = sB[buf];
        #pragma unroll
        for (int i = 0; i < 3; i++)
            if (i < nsw) gl16(gaB[i] + kk * 32, lb + (s0w + i) * 512);
    };

    auto stageA = [&](int dt, int kk) {
        #pragma unroll
        for (int s12 = 0; s12 < 12; s12++) {
            int pi = w * 12 + s12;
            int dp = pi >> 4, sub = pi & 15;
            gl16(W2s + (size_t)((dt * 3 + dp) * 4 + kk) * 8192 + sub * 512 + lane * 8,
                 sA + pi * 512);
        }
    };

    setmask(0, 0);
    setaddrB(0, 0);
    stageB(0, 0);
    stageA(0, 0);

    for (int ph = 0; ph < 36; ph++) {
        const int cur = ph & 1;
        const int pn = ph + 1;
        asm volatile("s_waitcnt vmcnt(0)" ::: "memory");
        __builtin_amdgcn_s_barrier();
        __builtin_amdgcn_sched_barrier(0);
        if (pn < 36) {
            if ((pn & 3) == 0) setaddrB(pn / 12, (pn / 4) % 3);
            stageB(cur ^ 1, pn & 3);
        }
        __builtin_amdgcn_sched_barrier(0);
        __builtin_amdgcn_s_setprio(1);
        {
            const unsigned short* lb = sB[cur];
            #pragma unroll
            for (int dp = 0; dp < 3; dp++) {
                #pragma unroll
                for (int ks = 0; ks < 2; ks++) {
                    bf16x8 Bf0 = *reinterpret_cast<const bf16x8*>(lb + locv[dp][0] + ks * 256);
                    bf16x8 Bf1 = *reinterpret_cast<const bf16x8*>(lb + locv[dp][1] + ks * 256);
                    #pragma unroll
                    for (int ri = 0; ri < 4; ri++) {
                        bf16x8 Af = *reinterpret_cast<const bf16x8*>(sA + dp * 8192 + arow32[ri] + ks * 256);
                        acc[ri][0] = __builtin_amdgcn_mfma_f32_32x32x16_bf16(Af, Bf0, acc[ri][0], 0, 0, 0);
                        acc[ri][1] = __builtin_amdgcn_mfma_f32_32x32x16_bf16(Af, Bf1, acc[ri][1], 0, 0, 0);
                    }
                }
            }
        }
        __builtin_amdgcn_s_setprio(0);
        asm volatile("s_waitcnt lgkmcnt(0)" ::: "memory");
        __builtin_amdgcn_sched_barrier(0);
        __builtin_amdgcn_s_barrier();
        if (pn < 36) {
            stageA((pn / 4) % 3, pn & 3);
            if ((pn & 3) == 0) setmask(pn / 12, (pn / 4) % 3);
        }
    }

    // ---- epilogue: y = xb + (acc + nv*b2)/3, then fused LayerNorm over D ----
    const float inv3 = 1.0f / 3.0f;
    const float fnv = (float)nv;
    float sum2[2] = {0.f, 0.f}, ssq2[2] = {0.f, 0.f};
    #pragma unroll
    for (int ri = 0; ri < 4; ri++) {
        #pragma unroll
        for (int ci = 0; ci < 2; ci++) {
            const int c = cols2[ci];
            #pragma unroll
            for (int t = 0; t < 4; t++) {
                const int dout = wm * 128 + ri * 32 + t * 8 + 4 * lh;
                const float4 bb = *reinterpret_cast<const float4*>(b2 + dout);
                const size_t xoff = ((size_t)b * L_ + c) * D_ + dout;
                const ushort4 xr4 = *reinterpret_cast<const ushort4*>(xb + xoff);
                float y0 = bf2f(xr4.x) + (acc[ri][ci][t * 4 + 0] + fnv * bb.x) * inv3;
                float y1 = bf2f(xr4.y) + (acc[ri][ci][t * 4 + 1] + fnv * bb.y) * inv3;
                float y2 = bf2f(xr4.z) + (acc[ri][ci][t * 4 + 2] + fnv * bb.z) * inv3;
                float y3 = bf2f(xr4.w) + (acc[ri][ci][t * 4 + 3] + fnv * bb.w) * inv3;
                acc[ri][ci][t * 4 + 0] = y0;
                acc[ri][ci][t * 4 + 1] = y1;
                acc[ri][ci][t * 4 + 2] = y2;
                acc[ri][ci][t * 4 + 3] = y3;
                sum2[ci] += y0 + y1 + y2 + y3;
                ssq2[ci] += y0 * y0 + y1 * y1 + y2 * y2 + y3 * y3;
            }
        }
    }
    #pragma unroll
    for (int ci = 0; ci < 2; ci++) {
        sum2[ci] += __shfl_xor(sum2[ci], 32);
        ssq2[ci] += __shfl_xor(ssq2[ci], 32);
    }
    float* red = (float*)&sB[0][0];
    if (lh == 0) {
        #pragma unroll
        for (int ci = 0; ci < 2; ci++) {
            red[((w * 2 + ci) * 32 + l31) * 2 + 0] = sum2[ci];
            red[((w * 2 + ci) * 32 + l31) * 2 + 1] = ssq2[ci];
        }
    }
    __syncthreads();
    float muv[2], invv[2];
    #pragma unroll
    for (int ci = 0; ci < 2; ci++) {
        float ts = red[((wn * 2 + ci) * 32 + l31) * 2 + 0] +
                   red[(((2 + wn) * 2 + ci) * 32 + l31) * 2 + 0];
        float tq = red[((wn * 2 + ci) * 32 + l31) * 2 + 1] +
                   red[(((2 + wn) * 2 + ci) * 32 + l31) * 2 + 1];
        float mu = ts * (1.0f / 256.0f);
        float var = tq * (1.0f / 256.0f) - mu * mu;
        muv[ci] = mu;
        invv[ci] = 1.0f / sqrtf(var + 1e-5f);
    }
    #pragma unroll
    for (int ri = 0; ri < 4; ri++) {
        #pragma unroll
        for (int ci = 0; ci < 2; ci++) {
            const int c = cols2[ci];
            const float mu = muv[ci], inv = invv[ci];
            #pragma unroll
            for (int t = 0; t < 4; t++) {
                const int dout = wm * 128 + ri * 32 + t * 8 + 4 * lh;
                const float4 g4 = *reinterpret_cast<const float4*>(gamma + dout);
                const float4 be4 = *reinterpret_cast<const float4*>(beta + dout);
                const size_t xoff = ((size_t)b * L_ + c) * D_ + dout;
                float4 o;
                o.x = (acc[ri][ci][t * 4 + 0] - mu) * inv * g4.x + be4.x;
                o.y = (acc[ri][ci][t * 4 + 1] - mu) * inv * g4.y + be4.y;
                o.z = (acc[ri][ci][t * 4 + 2] - mu) * inv * g4.z + be4.z;
                o.w = (acc[ri][ci][t * 4 + 3] - mu) * inv * g4.w + be4.w;
                *reinterpret_cast<float4*>(yout + xoff) = o;
            }
        }
    }
}

extern "C" void kernel_launch(void* const* d_in, const int* in_sizes, int n_in,
                              void* d_out, int out_size, void* d_ws, size_t ws_size,
                              hipStream_t stream) {
    const float* x     = (const float*)d_in[0];
    const float* W1    = (const float*)d_in[1];
    const float* b1    = (const float*)d_in[2];
    const float* W2    = (const float*)d_in[3];
    const float* b2    = (const float*)d_in[4];
    const float* gamma = (const float*)d_in[5];
    const float* beta  = (const float*)d_in[6];
    float* out = (float*)d_out;

    char* ws = (char*)d_ws;
    size_t off = 0;
    auto walloc = [&](size_t bytes) -> void* {
        void* pp = ws + off;
        off += (bytes + 255) & ~(size_t)255;
        return pp;
    };
    unsigned short* xb    = (unsigned short*)walloc((size_t)B_ * L_ * D_ * 2);
    unsigned short* out1g = (unsigned short*)walloc((size_t)B_ * 3 * LPMAX * C_ * 2);
    float* series         = (float*)walloc((size_t)B_ * L_ * 4);
    float* mag2           = (float*)walloc((size_t)B_ * 513 * 4);
    int* periods          = (int*)walloc((size_t)B_ * 3 * 4);
    double* tw            = (double*)walloc(1024 * 16);
    unsigned short* W1s   = (unsigned short*)walloc((size_t)294912 * 2);
    unsigned short* W2s   = (unsigned short*)walloc((size_t)294912 * 2);

    prep_kernel<<<B_ * L_ / 4, 256, 0, stream>>>(x, xb, series);
    repack_kernel<<<2308, 256, 0, stream>>>(W1, W2, W1s, W2s, tw);
    dft_kernel<<<(B_ * 513 + 3) / 4, 256, 0, stream>>>(series, tw, mag2);
    topk_kernel<<<B_, 64, 0, stream>>>(mag2, periods);
    conv1_kernel<<<B_ * 3 * 12, 256, 0, stream>>>(xb, W1s, b1, periods, out1g);
    conv2_kernel<<<B_ * 8, 256, 0, stream>>>(out1g, W2s, b2, periods, xb, gamma, beta, out);
}